// Round 1
// baseline (2619.957 us; speedup 1.0000x reference)
//
#include <hip/hip_runtime.h>
#include <math.h>

// ---------------- problem dims ----------------
// node: 16 x 0e + 8 x 1o ; edge: 8 x 0e + 8 x 1o
// hidden (TP out): 48 scalars (32 silu + 16 gates), 16 vectors
// output: 16 x 0e + 8 x 1o  -> [N, 40]

// path normalization constants (i2 = 1/sqrt2, i3 = 1/sqrt3 folded in)
constexpr float C_SS16 = 0.04419417382415922f;  // i2/16            (ss, stage 1 & 3)
constexpr float C_UNI  = 0.05103103630798288f;  // i2*i3/8 == i3/sqrt(128) (most paths)
constexpr float C2_SS  = 0.0625f;               // i2/sqrt(128)     (ss, stage 2)
constexpr float C2_VS  = 0.07216878364870323f;  // i3/8             (vs, stage 2)
constexpr float C_LS   = 0.17677669529663687f;  // 1/sqrt(32)  lin scalars
constexpr float C_LV   = 0.25f;                 // 1/sqrt(16)  lin vectors

// =====================================================================
// Edge kernel: stage1 TP(node[row], node[col]) -> (ms[16], mv[8][3]) in LDS,
// stage2 TP(m, edge_attr) -> (hs[48], hv[16][3]), gate, linear, atomic scatter.
// =====================================================================
__global__ __launch_bounds__(256)
void edge_kernel(const float* __restrict__ node_s, const float* __restrict__ node_v,
                 const float* __restrict__ edge_s, const float* __restrict__ edge_v,
                 const int* __restrict__ ei,
                 const float* __restrict__ W1ss, const float* __restrict__ W1sv,
                 const float* __restrict__ W1vs, const float* __restrict__ W1vvs,
                 const float* __restrict__ W1vvv,
                 const float* __restrict__ W2ss, const float* __restrict__ W2sv,
                 const float* __restrict__ W2vs, const float* __restrict__ W2vvs,
                 const float* __restrict__ W2vvv,
                 const float* __restrict__ Lms, const float* __restrict__ Lmv,
                 float* __restrict__ agg, int E)
{
    __shared__ float lds[256 * 41];   // 41984 B; stride 41 -> conflict-free (gcd(9,32)=1)
    const int tid = threadIdx.x;
    const int e = blockIdx.x * 256 + tid;
    if (e >= E) return;
    float* my = &lds[tid * 41];

    const int row = ei[e];
    const int col = ei[E + e];
    const float* rs = node_s + row * 16;
    const float* rv = node_v + row * 24;
    const float* cs = node_s + col * 16;
    const float* cv = node_v + col * 24;
    const float* es = edge_s + e * 8;
    const float* ev = edge_v + e * 24;

    // ================= stage 1 =================
    {
        float ms[16];
        #pragma unroll
        for (int k = 0; k < 16; ++k) ms[k] = 0.f;
        float mvx[8], mvy[8], mvz[8];
        #pragma unroll
        for (int k = 0; k < 8; ++k) { mvx[k] = 0.f; mvy[k] = 0.f; mvz[k] = 0.f; }

        // ss: ms[k] += c * s1[i] s2[j] W1ss[i,j,k]
        #pragma unroll 1
        for (int i = 0; i < 16; ++i) {
            const float a = rs[i] * C_SS16;
            #pragma unroll 1
            for (int j = 0; j < 16; ++j) {
                const float p = a * cs[j];
                const float* w = W1ss + (i * 16 + j) * 16;
                #pragma unroll
                for (int k = 0; k < 16; ++k) ms[k] = fmaf(p, w[k], ms[k]);
            }
        }
        // vvs: ms[k] += c * (v1[i].v2[j]) W1vvs[i,j,k]
        #pragma unroll 1
        for (int i = 0; i < 8; ++i) {
            const float ax = rv[i*3], ay = rv[i*3+1], az = rv[i*3+2];
            #pragma unroll 1
            for (int j = 0; j < 8; ++j) {
                const float d = fmaf(ax, cv[j*3], fmaf(ay, cv[j*3+1], az * cv[j*3+2])) * C_UNI;
                const float* w = W1vvs + (i * 8 + j) * 16;
                #pragma unroll
                for (int k = 0; k < 16; ++k) ms[k] = fmaf(d, w[k], ms[k]);
            }
        }
        // sv: mv[k,c] += c * s1[i] v2[j,c] W1sv[i,j,k]   (t[k] = sum_i s1[i] W)
        #pragma unroll 1
        for (int j = 0; j < 8; ++j) {
            float t[8];
            #pragma unroll
            for (int k = 0; k < 8; ++k) t[k] = 0.f;
            #pragma unroll 1
            for (int i = 0; i < 16; ++i) {
                const float a = rs[i];
                const float* w = W1sv + (i * 8 + j) * 8;
                #pragma unroll
                for (int k = 0; k < 8; ++k) t[k] = fmaf(a, w[k], t[k]);
            }
            const float bx = cv[j*3]*C_UNI, by = cv[j*3+1]*C_UNI, bz = cv[j*3+2]*C_UNI;
            #pragma unroll
            for (int k = 0; k < 8; ++k) {
                mvx[k] = fmaf(t[k], bx, mvx[k]);
                mvy[k] = fmaf(t[k], by, mvy[k]);
                mvz[k] = fmaf(t[k], bz, mvz[k]);
            }
        }
        // vs: mv[k,c] += c * v1[i,c] s2[j] W1vs[i,j,k]   (t[k] = sum_j s2[j] W)
        #pragma unroll 1
        for (int i = 0; i < 8; ++i) {
            float t[8];
            #pragma unroll
            for (int k = 0; k < 8; ++k) t[k] = 0.f;
            #pragma unroll 1
            for (int j = 0; j < 16; ++j) {
                const float b = cs[j];
                const float* w = W1vs + (i * 16 + j) * 8;
                #pragma unroll
                for (int k = 0; k < 8; ++k) t[k] = fmaf(b, w[k], t[k]);
            }
            const float ax = rv[i*3]*C_UNI, ay = rv[i*3+1]*C_UNI, az = rv[i*3+2]*C_UNI;
            #pragma unroll
            for (int k = 0; k < 8; ++k) {
                mvx[k] = fmaf(t[k], ax, mvx[k]);
                mvy[k] = fmaf(t[k], ay, mvy[k]);
                mvz[k] = fmaf(t[k], az, mvz[k]);
            }
        }
        // vvv: mv[k,c] += c * (v1[i] x v2[j])_c W1vvv[i,j,k]
        #pragma unroll 1
        for (int i = 0; i < 8; ++i) {
            const float ax = rv[i*3], ay = rv[i*3+1], az = rv[i*3+2];
            #pragma unroll 1
            for (int j = 0; j < 8; ++j) {
                const float bx = cv[j*3], by = cv[j*3+1], bz = cv[j*3+2];
                const float cx = (ay*bz - az*by) * C_UNI;
                const float cy = (az*bx - ax*bz) * C_UNI;
                const float cz = (ax*by - ay*bx) * C_UNI;
                const float* w = W1vvv + (i * 8 + j) * 8;
                #pragma unroll
                for (int k = 0; k < 8; ++k) {
                    mvx[k] = fmaf(cx, w[k], mvx[k]);
                    mvy[k] = fmaf(cy, w[k], mvy[k]);
                    mvz[k] = fmaf(cz, w[k], mvz[k]);
                }
            }
        }
        // park in private LDS slot so stage 2 can roll its i-loops
        #pragma unroll
        for (int k = 0; k < 16; ++k) my[k] = ms[k];
        #pragma unroll
        for (int k = 0; k < 8; ++k) {
            my[16 + k*3]     = mvx[k];
            my[16 + k*3 + 1] = mvy[k];
            my[16 + k*3 + 2] = mvz[k];
        }
    }

    // ================= stage 2 =================
    float hs[48];
    #pragma unroll
    for (int k = 0; k < 48; ++k) hs[k] = 0.f;
    float hvx[16], hvy[16], hvz[16];
    #pragma unroll
    for (int k = 0; k < 16; ++k) { hvx[k] = 0.f; hvy[k] = 0.f; hvz[k] = 0.f; }

    // ss2: hs[k] += c * ms[i] es[j] W2ss[i,j,k]
    #pragma unroll 1
    for (int j = 0; j < 8; ++j) {
        const float b = es[j] * C2_SS;
        #pragma unroll 1
        for (int i = 0; i < 16; ++i) {
            const float p = my[i] * b;
            const float* w = W2ss + (i * 8 + j) * 48;
            #pragma unroll
            for (int k = 0; k < 48; ++k) hs[k] = fmaf(p, w[k], hs[k]);
        }
    }
    // vvs2: hs[k] += c * (mv[i].ev[j]) W2vvs[i,j,k]
    #pragma unroll 1
    for (int j = 0; j < 8; ++j) {
        const float bx = ev[j*3], by = ev[j*3+1], bz = ev[j*3+2];
        #pragma unroll 1
        for (int i = 0; i < 8; ++i) {
            const float* m = my + 16 + i * 3;
            const float d = fmaf(m[0], bx, fmaf(m[1], by, m[2] * bz)) * C_UNI;
            const float* w = W2vvs + (i * 8 + j) * 48;
            #pragma unroll
            for (int k = 0; k < 48; ++k) hs[k] = fmaf(d, w[k], hs[k]);
        }
    }
    // sv2: hv[k,c] += c * ms[i] ev[j,c] W2sv[i,j,k]
    #pragma unroll 1
    for (int j = 0; j < 8; ++j) {
        float t[16];
        #pragma unroll
        for (int k = 0; k < 16; ++k) t[k] = 0.f;
        #pragma unroll 1
        for (int i = 0; i < 16; ++i) {
            const float a = my[i];
            const float* w = W2sv + (i * 8 + j) * 16;
            #pragma unroll
            for (int k = 0; k < 16; ++k) t[k] = fmaf(a, w[k], t[k]);
        }
        const float bx = ev[j*3]*C_UNI, by = ev[j*3+1]*C_UNI, bz = ev[j*3+2]*C_UNI;
        #pragma unroll
        for (int k = 0; k < 16; ++k) {
            hvx[k] = fmaf(t[k], bx, hvx[k]);
            hvy[k] = fmaf(t[k], by, hvy[k]);
            hvz[k] = fmaf(t[k], bz, hvz[k]);
        }
    }
    // vs2: hv[k,c] += c * mv[i,c] es[j] W2vs[i,j,k]
    #pragma unroll 1
    for (int i = 0; i < 8; ++i) {
        float t[16];
        #pragma unroll
        for (int k = 0; k < 16; ++k) t[k] = 0.f;
        #pragma unroll 1
        for (int j = 0; j < 8; ++j) {
            const float b = es[j];
            const float* w = W2vs + (i * 8 + j) * 16;
            #pragma unroll
            for (int k = 0; k < 16; ++k) t[k] = fmaf(b, w[k], t[k]);
        }
        const float ax = my[16+i*3]*C2_VS, ay = my[16+i*3+1]*C2_VS, az = my[16+i*3+2]*C2_VS;
        #pragma unroll
        for (int k = 0; k < 16; ++k) {
            hvx[k] = fmaf(t[k], ax, hvx[k]);
            hvy[k] = fmaf(t[k], ay, hvy[k]);
            hvz[k] = fmaf(t[k], az, hvz[k]);
        }
    }
    // vvv2: hv[k,c] += c * (mv[i] x ev[j])_c W2vvv[i,j,k]
    #pragma unroll 1
    for (int j = 0; j < 8; ++j) {
        const float bx = ev[j*3], by = ev[j*3+1], bz = ev[j*3+2];
        #pragma unroll 1
        for (int i = 0; i < 8; ++i) {
            const float ax = my[16+i*3], ay = my[16+i*3+1], az = my[16+i*3+2];
            const float cx = (ay*bz - az*by) * C_UNI;
            const float cy = (az*bx - ax*bz) * C_UNI;
            const float cz = (ax*by - ay*bx) * C_UNI;
            const float* w = W2vvv + (i * 8 + j) * 16;
            #pragma unroll
            for (int k = 0; k < 16; ++k) {
                hvx[k] = fmaf(cx, w[k], hvx[k]);
                hvy[k] = fmaf(cy, w[k], hvy[k]);
                hvz[k] = fmaf(cz, w[k], hvz[k]);
            }
        }
    }

    // ============ gate + linear (Lms/Lmv) ============
    float os[16];
    #pragma unroll
    for (int k = 0; k < 16; ++k) os[k] = 0.f;
    float ovx[8], ovy[8], ovz[8];
    #pragma unroll
    for (int k = 0; k < 8; ++k) { ovx[k] = 0.f; ovy[k] = 0.f; ovz[k] = 0.f; }

    #pragma unroll
    for (int i = 0; i < 32; ++i) {
        const float x = hs[i];
        const float a = x / (1.f + __expf(-x)) * C_LS;   // silu * 1/sqrt(32)
        const float* w = Lms + i * 16;
        #pragma unroll
        for (int k = 0; k < 16; ++k) os[k] = fmaf(a, w[k], os[k]);
    }
    #pragma unroll
    for (int i = 0; i < 16; ++i) {
        const float g = C_LV / (1.f + __expf(-hs[32 + i]));  // sigmoid * 1/sqrt(16)
        const float gx = hvx[i]*g, gy = hvy[i]*g, gz = hvz[i]*g;
        const float* w = Lmv + i * 8;
        #pragma unroll
        for (int k = 0; k < 8; ++k) {
            ovx[k] = fmaf(gx, w[k], ovx[k]);
            ovy[k] = fmaf(gy, w[k], ovy[k]);
            ovz[k] = fmaf(gz, w[k], ovz[k]);
        }
    }

    // scatter-sum into agg[col, 0:40]
    float* dst = agg + (size_t)col * 40;
    #pragma unroll
    for (int k = 0; k < 16; ++k) atomicAdd(dst + k, os[k]);
    #pragma unroll
    for (int k = 0; k < 8; ++k) {
        atomicAdd(dst + 16 + k*3,     ovx[k]);
        atomicAdd(dst + 16 + k*3 + 1, ovy[k]);
        atomicAdd(dst + 16 + k*3 + 2, ovz[k]);
    }
}

// =====================================================================
// Node kernel: TP(node, agg) -> gate -> linear -> out[N,40]
// =====================================================================
__global__ __launch_bounds__(256)
void node_kernel(const float* __restrict__ node_s, const float* __restrict__ node_v,
                 const float* __restrict__ agg,
                 const float* __restrict__ W3ss, const float* __restrict__ W3sv,
                 const float* __restrict__ W3vs, const float* __restrict__ W3vvs,
                 const float* __restrict__ W3vvv,
                 const float* __restrict__ Lus, const float* __restrict__ Luv,
                 float* __restrict__ out, int N)
{
    const int n = blockIdx.x * 256 + threadIdx.x;
    if (n >= N) return;
    const float* rs = node_s + n * 16;           // i-side scalars (16)
    const float* rv = node_v + n * 24;           // i-side vectors (8)
    const float* cs = agg + (size_t)n * 40;      // j-side scalars (16)
    const float* cv = cs + 16;                   // j-side vectors (8), [k*3+c]

    float hs[48];
    #pragma unroll
    for (int k = 0; k < 48; ++k) hs[k] = 0.f;
    float hvx[16], hvy[16], hvz[16];
    #pragma unroll
    for (int k = 0; k < 16; ++k) { hvx[k] = 0.f; hvy[k] = 0.f; hvz[k] = 0.f; }

    // ss3: i16 j16 k48
    #pragma unroll 1
    for (int i = 0; i < 16; ++i) {
        const float a = rs[i] * C_SS16;
        #pragma unroll 1
        for (int j = 0; j < 16; ++j) {
            const float p = a * cs[j];
            const float* w = W3ss + (i * 16 + j) * 48;
            #pragma unroll
            for (int k = 0; k < 48; ++k) hs[k] = fmaf(p, w[k], hs[k]);
        }
    }
    // vvs3: i8 j8 k48
    #pragma unroll 1
    for (int i = 0; i < 8; ++i) {
        const float ax = rv[i*3], ay = rv[i*3+1], az = rv[i*3+2];
        #pragma unroll 1
        for (int j = 0; j < 8; ++j) {
            const float d = fmaf(ax, cv[j*3], fmaf(ay, cv[j*3+1], az * cv[j*3+2])) * C_UNI;
            const float* w = W3vvs + (i * 8 + j) * 48;
            #pragma unroll
            for (int k = 0; k < 48; ++k) hs[k] = fmaf(d, w[k], hs[k]);
        }
    }
    // sv3: i16 j8 k16
    #pragma unroll 1
    for (int j = 0; j < 8; ++j) {
        float t[16];
        #pragma unroll
        for (int k = 0; k < 16; ++k) t[k] = 0.f;
        #pragma unroll 1
        for (int i = 0; i < 16; ++i) {
            const float a = rs[i];
            const float* w = W3sv + (i * 8 + j) * 16;
            #pragma unroll
            for (int k = 0; k < 16; ++k) t[k] = fmaf(a, w[k], t[k]);
        }
        const float bx = cv[j*3]*C_UNI, by = cv[j*3+1]*C_UNI, bz = cv[j*3+2]*C_UNI;
        #pragma unroll
        for (int k = 0; k < 16; ++k) {
            hvx[k] = fmaf(t[k], bx, hvx[k]);
            hvy[k] = fmaf(t[k], by, hvy[k]);
            hvz[k] = fmaf(t[k], bz, hvz[k]);
        }
    }
    // vs3: i8 j16 k16
    #pragma unroll 1
    for (int i = 0; i < 8; ++i) {
        float t[16];
        #pragma unroll
        for (int k = 0; k < 16; ++k) t[k] = 0.f;
        #pragma unroll 1
        for (int j = 0; j < 16; ++j) {
            const float b = cs[j];
            const float* w = W3vs + (i * 16 + j) * 16;
            #pragma unroll
            for (int k = 0; k < 16; ++k) t[k] = fmaf(b, w[k], t[k]);
        }
        const float ax = rv[i*3]*C_UNI, ay = rv[i*3+1]*C_UNI, az = rv[i*3+2]*C_UNI;
        #pragma unroll
        for (int k = 0; k < 16; ++k) {
            hvx[k] = fmaf(t[k], ax, hvx[k]);
            hvy[k] = fmaf(t[k], ay, hvy[k]);
            hvz[k] = fmaf(t[k], az, hvz[k]);
        }
    }
    // vvv3: i8 j8 k16
    #pragma unroll 1
    for (int i = 0; i < 8; ++i) {
        const float ax = rv[i*3], ay = rv[i*3+1], az = rv[i*3+2];
        #pragma unroll 1
        for (int j = 0; j < 8; ++j) {
            const float bx = cv[j*3], by = cv[j*3+1], bz = cv[j*3+2];
            const float cx = (ay*bz - az*by) * C_UNI;
            const float cy = (az*bx - ax*bz) * C_UNI;
            const float cz = (ax*by - ay*bx) * C_UNI;
            const float* w = W3vvv + (i * 8 + j) * 16;
            #pragma unroll
            for (int k = 0; k < 16; ++k) {
                hvx[k] = fmaf(cx, w[k], hvx[k]);
                hvy[k] = fmaf(cy, w[k], hvy[k]);
                hvz[k] = fmaf(cz, w[k], hvz[k]);
            }
        }
    }

    // gate + linear (Lus/Luv)
    float os[16];
    #pragma unroll
    for (int k = 0; k < 16; ++k) os[k] = 0.f;
    float ovx[8], ovy[8], ovz[8];
    #pragma unroll
    for (int k = 0; k < 8; ++k) { ovx[k] = 0.f; ovy[k] = 0.f; ovz[k] = 0.f; }

    #pragma unroll
    for (int i = 0; i < 32; ++i) {
        const float x = hs[i];
        const float a = x / (1.f + __expf(-x)) * C_LS;
        const float* w = Lus + i * 16;
        #pragma unroll
        for (int k = 0; k < 16; ++k) os[k] = fmaf(a, w[k], os[k]);
    }
    #pragma unroll
    for (int i = 0; i < 16; ++i) {
        const float g = C_LV / (1.f + __expf(-hs[32 + i]));
        const float gx = hvx[i]*g, gy = hvy[i]*g, gz = hvz[i]*g;
        const float* w = Luv + i * 8;
        #pragma unroll
        for (int k = 0; k < 8; ++k) {
            ovx[k] = fmaf(gx, w[k], ovx[k]);
            ovy[k] = fmaf(gy, w[k], ovy[k]);
            ovz[k] = fmaf(gz, w[k], ovz[k]);
        }
    }

    // pack [us(16) | uv(8,3) flattened] and store as float4s
    float ob[40];
    #pragma unroll
    for (int k = 0; k < 16; ++k) ob[k] = os[k];
    #pragma unroll
    for (int k = 0; k < 8; ++k) {
        ob[16 + k*3]     = ovx[k];
        ob[16 + k*3 + 1] = ovy[k];
        ob[16 + k*3 + 2] = ovz[k];
    }
    float4* o4 = (float4*)(out + (size_t)n * 40);
    #pragma unroll
    for (int q = 0; q < 10; ++q)
        o4[q] = make_float4(ob[4*q], ob[4*q+1], ob[4*q+2], ob[4*q+3]);
}

// =====================================================================
extern "C" void kernel_launch(void* const* d_in, const int* in_sizes, int n_in,
                              void* d_out, int out_size, void* d_ws, size_t ws_size,
                              hipStream_t stream) {
    const float* node_s = (const float*)d_in[0];
    const float* node_v = (const float*)d_in[1];
    // d_in[2] = pos (unused by reference)
    const float* edge_s = (const float*)d_in[3];
    const float* edge_v = (const float*)d_in[4];
    const int*   ei     = (const int*)d_in[5];
    const float* W1ss = (const float*)d_in[6];
    const float* W1sv = (const float*)d_in[7];
    const float* W1vs = (const float*)d_in[8];
    const float* W1vvs= (const float*)d_in[9];
    const float* W1vvv= (const float*)d_in[10];
    const float* W2ss = (const float*)d_in[11];
    const float* W2sv = (const float*)d_in[12];
    const float* W2vs = (const float*)d_in[13];
    const float* W2vvs= (const float*)d_in[14];
    const float* W2vvv= (const float*)d_in[15];
    const float* Lms  = (const float*)d_in[16];
    const float* Lmv  = (const float*)d_in[17];
    const float* W3ss = (const float*)d_in[18];
    const float* W3sv = (const float*)d_in[19];
    const float* W3vs = (const float*)d_in[20];
    const float* W3vvs= (const float*)d_in[21];
    const float* W3vvv= (const float*)d_in[22];
    const float* Lus  = (const float*)d_in[23];
    const float* Luv  = (const float*)d_in[24];

    float* out = (float*)d_out;
    float* agg = (float*)d_ws;          // [N, 40] aggregation buffer

    const int N = in_sizes[0] / 16;
    const int E = in_sizes[5] / 2;

    hipMemsetAsync(agg, 0, (size_t)N * 40 * sizeof(float), stream);

    edge_kernel<<<(E + 255) / 256, 256, 0, stream>>>(
        node_s, node_v, edge_s, edge_v, ei,
        W1ss, W1sv, W1vs, W1vvs, W1vvv,
        W2ss, W2sv, W2vs, W2vvs, W2vvv,
        Lms, Lmv, agg, E);

    node_kernel<<<(N + 255) / 256, 256, 0, stream>>>(
        node_s, node_v, agg,
        W3ss, W3sv, W3vs, W3vvs, W3vvv,
        Lus, Luv, out, N);
}

// Round 2
// 1486.842 us; speedup vs baseline: 1.7621x; 1.7621x over previous
//
#include <hip/hip_runtime.h>
#include <math.h>

// ---------------- problem dims ----------------
// node: 16 x 0e + 8 x 1o ; edge: 8 x 0e + 8 x 1o
// hidden (TP out): 48 scalars (32 silu + 16 gates), 16 vectors
// output: 16 x 0e + 8 x 1o  -> [N, 40]

constexpr float C_SS16 = 0.04419417382415922f;  // i2/16
constexpr float C_UNI  = 0.05103103630798288f;  // i3/sqrt(128)
constexpr float C2_SS  = 0.0625f;               // i2/sqrt(128)
constexpr float C2_VS  = 0.07216878364870323f;  // i3/8
constexpr float C_LS   = 0.17677669529663687f;  // 1/sqrt(32)
constexpr float C_LV   = 0.25f;                 // 1/sqrt(16)

// ---- helpers: acc[0:K] += p * w[0:K], w via float4 (ds_read_b128 on LDS) ----
__device__ __forceinline__ void fma8(float* acc, float p, const float4* w4) {
#pragma unroll
    for (int kk = 0; kk < 2; ++kk) {
        float4 w = w4[kk];
        acc[4*kk+0] = fmaf(p, w.x, acc[4*kk+0]);
        acc[4*kk+1] = fmaf(p, w.y, acc[4*kk+1]);
        acc[4*kk+2] = fmaf(p, w.z, acc[4*kk+2]);
        acc[4*kk+3] = fmaf(p, w.w, acc[4*kk+3]);
    }
}
__device__ __forceinline__ void fma16(float* acc, float p, const float4* w4) {
#pragma unroll
    for (int kk = 0; kk < 4; ++kk) {
        float4 w = w4[kk];
        acc[4*kk+0] = fmaf(p, w.x, acc[4*kk+0]);
        acc[4*kk+1] = fmaf(p, w.y, acc[4*kk+1]);
        acc[4*kk+2] = fmaf(p, w.z, acc[4*kk+2]);
        acc[4*kk+3] = fmaf(p, w.w, acc[4*kk+3]);
    }
}
__device__ __forceinline__ void fma48(float* acc, float p, const float4* w4) {
#pragma unroll
    for (int kk = 0; kk < 12; ++kk) {
        float4 w = w4[kk];
        acc[4*kk+0] = fmaf(p, w.x, acc[4*kk+0]);
        acc[4*kk+1] = fmaf(p, w.y, acc[4*kk+1]);
        acc[4*kk+2] = fmaf(p, w.z, acc[4*kk+2]);
        acc[4*kk+3] = fmaf(p, w.w, acc[4*kk+3]);
    }
}
// vector accumulators: each weight element feeds 3 fmas (x,y,z)
__device__ __forceinline__ void vfma8(float* ax_, float* ay_, float* az_,
                                      float cx, float cy, float cz, const float4* w4) {
#pragma unroll
    for (int kk = 0; kk < 2; ++kk) {
        float4 w = w4[kk];
        ax_[4*kk+0]=fmaf(cx,w.x,ax_[4*kk+0]); ay_[4*kk+0]=fmaf(cy,w.x,ay_[4*kk+0]); az_[4*kk+0]=fmaf(cz,w.x,az_[4*kk+0]);
        ax_[4*kk+1]=fmaf(cx,w.y,ax_[4*kk+1]); ay_[4*kk+1]=fmaf(cy,w.y,ay_[4*kk+1]); az_[4*kk+1]=fmaf(cz,w.y,az_[4*kk+1]);
        ax_[4*kk+2]=fmaf(cx,w.z,ax_[4*kk+2]); ay_[4*kk+2]=fmaf(cy,w.z,ay_[4*kk+2]); az_[4*kk+2]=fmaf(cz,w.z,az_[4*kk+2]);
        ax_[4*kk+3]=fmaf(cx,w.w,ax_[4*kk+3]); ay_[4*kk+3]=fmaf(cy,w.w,ay_[4*kk+3]); az_[4*kk+3]=fmaf(cz,w.w,az_[4*kk+3]);
    }
}
__device__ __forceinline__ void vfma16(float* ax_, float* ay_, float* az_,
                                       float cx, float cy, float cz, const float4* w4) {
#pragma unroll
    for (int kk = 0; kk < 4; ++kk) {
        float4 w = w4[kk];
        ax_[4*kk+0]=fmaf(cx,w.x,ax_[4*kk+0]); ay_[4*kk+0]=fmaf(cy,w.x,ay_[4*kk+0]); az_[4*kk+0]=fmaf(cz,w.x,az_[4*kk+0]);
        ax_[4*kk+1]=fmaf(cx,w.y,ax_[4*kk+1]); ay_[4*kk+1]=fmaf(cy,w.y,ay_[4*kk+1]); az_[4*kk+1]=fmaf(cz,w.y,az_[4*kk+1]);
        ax_[4*kk+2]=fmaf(cx,w.z,ax_[4*kk+2]); ay_[4*kk+2]=fmaf(cy,w.z,ay_[4*kk+2]); az_[4*kk+2]=fmaf(cz,w.z,az_[4*kk+2]);
        ax_[4*kk+3]=fmaf(cx,w.w,ax_[4*kk+3]); ay_[4*kk+3]=fmaf(cy,w.w,ay_[4*kk+3]); az_[4*kk+3]=fmaf(cz,w.w,az_[4*kk+3]);
    }
}

// =====================================================================
// K1: stage-1 TP(node[row], node[col]) -> m_t[40][E]  (transposed!)
// LDS: W1 (30 KB) + per-thread feature scratch (rs16|cs16|cv24, stride 57)
// =====================================================================
__global__ __launch_bounds__(128)
void edge_tp1(const float* __restrict__ node_s, const float* __restrict__ node_v,
              const int* __restrict__ ei,
              const float* __restrict__ gW1ss, const float* __restrict__ gW1sv,
              const float* __restrict__ gW1vs, const float* __restrict__ gW1vvs,
              const float* __restrict__ gW1vvv,
              float* __restrict__ m_t, int E)
{
    __shared__ __align__(16) float wss[4096], wsv[1024], wvs[1024], wvvs[1024], wvvv[512];
    __shared__ float sc_all[128 * 57];   // stride 57: 57%32=25, gcd(25,32)=1 -> conflict-free
    const int tid = threadIdx.x;
    {
        float4* d; const float4* s;
        d=(float4*)wss;  s=(const float4*)gW1ss;  for (int i=tid;i<1024;i+=128) d[i]=s[i];
        d=(float4*)wsv;  s=(const float4*)gW1sv;  for (int i=tid;i<256; i+=128) d[i]=s[i];
        d=(float4*)wvs;  s=(const float4*)gW1vs;  for (int i=tid;i<256; i+=128) d[i]=s[i];
        d=(float4*)wvvs; s=(const float4*)gW1vvs; for (int i=tid;i<256; i+=128) d[i]=s[i];
        d=(float4*)wvvv; s=(const float4*)gW1vvv; if (tid<128) d[tid]=s[tid];
    }
    __syncthreads();
    const int e = blockIdx.x * 128 + tid;
    if (e >= E) return;

    const int row = ei[e], col = ei[E + e];
    float* sc = sc_all + tid * 57;
    {   // gather features once (float4 global), park in private LDS slot
        const float4* p = (const float4*)(node_s + (size_t)row * 16);
#pragma unroll
        for (int q=0;q<4;++q){ float4 t=p[q]; sc[4*q]=t.x; sc[4*q+1]=t.y; sc[4*q+2]=t.z; sc[4*q+3]=t.w; }
        p = (const float4*)(node_s + (size_t)col * 16);
#pragma unroll
        for (int q=0;q<4;++q){ float4 t=p[q]; sc[16+4*q]=t.x; sc[16+4*q+1]=t.y; sc[16+4*q+2]=t.z; sc[16+4*q+3]=t.w; }
        p = (const float4*)(node_v + (size_t)col * 24);
#pragma unroll
        for (int q=0;q<6;++q){ float4 t=p[q]; sc[32+4*q]=t.x; sc[32+4*q+1]=t.y; sc[32+4*q+2]=t.z; sc[32+4*q+3]=t.w; }
    }
    const float* rv = node_v + (size_t)row * 24;

    float ms[16];
#pragma unroll
    for (int k=0;k<16;++k) ms[k]=0.f;
    float mvx[8], mvy[8], mvz[8];
#pragma unroll
    for (int k=0;k<8;++k){ mvx[k]=0.f; mvy[k]=0.f; mvz[k]=0.f; }

    // ss1
#pragma unroll 1
    for (int i=0;i<16;++i) {
        const float a = sc[i]*C_SS16;
#pragma unroll 2
        for (int j=0;j<16;++j)
            fma16(ms, a*sc[16+j], (const float4*)&wss[(i*16+j)*16]);
    }
    // vvs1
#pragma unroll 1
    for (int i=0;i<8;++i) {
        const float ax=rv[3*i], ay=rv[3*i+1], az=rv[3*i+2];
#pragma unroll 2
        for (int j=0;j<8;++j) {
            const float* c = &sc[32+3*j];
            const float d = fmaf(ax,c[0],fmaf(ay,c[1],az*c[2]))*C_UNI;
            fma16(ms, d, (const float4*)&wvvs[(i*8+j)*16]);
        }
    }
    // sv1
#pragma unroll 1
    for (int j=0;j<8;++j) {
        float t[8];
#pragma unroll
        for (int k=0;k<8;++k) t[k]=0.f;
#pragma unroll 2
        for (int i=0;i<16;++i)
            fma8(t, sc[i], (const float4*)&wsv[(i*8+j)*8]);
        const float bx=sc[32+3*j]*C_UNI, by=sc[32+3*j+1]*C_UNI, bz=sc[32+3*j+2]*C_UNI;
#pragma unroll
        for (int k=0;k<8;++k){ mvx[k]=fmaf(t[k],bx,mvx[k]); mvy[k]=fmaf(t[k],by,mvy[k]); mvz[k]=fmaf(t[k],bz,mvz[k]); }
    }
    // vs1
#pragma unroll 1
    for (int i=0;i<8;++i) {
        float t[8];
#pragma unroll
        for (int k=0;k<8;++k) t[k]=0.f;
#pragma unroll 2
        for (int j=0;j<16;++j)
            fma8(t, sc[16+j], (const float4*)&wvs[(i*16+j)*8]);
        const float ax=rv[3*i]*C_UNI, ay=rv[3*i+1]*C_UNI, az=rv[3*i+2]*C_UNI;
#pragma unroll
        for (int k=0;k<8;++k){ mvx[k]=fmaf(t[k],ax,mvx[k]); mvy[k]=fmaf(t[k],ay,mvy[k]); mvz[k]=fmaf(t[k],az,mvz[k]); }
    }
    // vvv1
#pragma unroll 1
    for (int i=0;i<8;++i) {
        const float ax=rv[3*i], ay=rv[3*i+1], az=rv[3*i+2];
#pragma unroll 2
        for (int j=0;j<8;++j) {
            const float* c=&sc[32+3*j];
            const float bx=c[0], by=c[1], bz=c[2];
            const float cx=(ay*bz-az*by)*C_UNI, cy=(az*bx-ax*bz)*C_UNI, cz=(ax*by-ay*bx)*C_UNI;
            vfma8(mvx,mvy,mvz, cx,cy,cz, (const float4*)&wvvv[(i*8+j)*8]);
        }
    }
    // store transposed -> coalesced loads in K2
#pragma unroll
    for (int k=0;k<16;++k) m_t[(size_t)k*E + e] = ms[k];
#pragma unroll
    for (int k=0;k<8;++k) {
        m_t[(size_t)(16+3*k+0)*E + e] = mvx[k];
        m_t[(size_t)(16+3*k+1)*E + e] = mvy[k];
        m_t[(size_t)(16+3*k+2)*E + e] = mvz[k];
    }
}

// =====================================================================
// K2: stage-2 TP(m, edge_attr) -> gate -> linear -> atomic scatter agg_t[40][N]
// LDS: W2 + Lm (54.5 KB). m reads coalesced via m_t.
// =====================================================================
__global__ __launch_bounds__(256)
void edge_tp2(const float* __restrict__ m_t,
              const float* __restrict__ edge_s, const float* __restrict__ edge_v,
              const int* __restrict__ ei,
              const float* __restrict__ gW2ss, const float* __restrict__ gW2sv,
              const float* __restrict__ gW2vs, const float* __restrict__ gW2vvs,
              const float* __restrict__ gW2vvv,
              const float* __restrict__ gLms, const float* __restrict__ gLmv,
              float* __restrict__ agg_t, int E, int N)
{
    __shared__ __align__(16) float wss[6144], wsv[2048], wvs[1024], wvvs[3072], wvvv[1024], lms[512], lmv[128];
    const int tid = threadIdx.x;
    {
        float4* d; const float4* s;
        d=(float4*)wss;  s=(const float4*)gW2ss;  for(int i=tid;i<1536;i+=256) d[i]=s[i];
        d=(float4*)wsv;  s=(const float4*)gW2sv;  for(int i=tid;i<512; i+=256) d[i]=s[i];
        d=(float4*)wvs;  s=(const float4*)gW2vs;  if(tid<256) d[tid]=s[tid];
        d=(float4*)wvvs; s=(const float4*)gW2vvs; for(int i=tid;i<768; i+=256) d[i]=s[i];
        d=(float4*)wvvv; s=(const float4*)gW2vvv; if(tid<256) d[tid]=s[tid];
        d=(float4*)lms;  s=(const float4*)gLms;   if(tid<128) d[tid]=s[tid];
        d=(float4*)lmv;  s=(const float4*)gLmv;   if(tid<32)  d[tid]=s[tid];
    }
    __syncthreads();
    const int e = blockIdx.x*256 + tid;
    if (e >= E) return;
    const int col = ei[E+e];
    const float* es = edge_s + (size_t)e*8;
    const float* ev = edge_v + (size_t)e*24;
#define MT(f) m_t[(size_t)(f)*E + e]

    float hs[48];
#pragma unroll
    for (int k=0;k<48;++k) hs[k]=0.f;
    float hvx[16],hvy[16],hvz[16];
#pragma unroll
    for (int k=0;k<16;++k){ hvx[k]=0.f; hvy[k]=0.f; hvz[k]=0.f; }

    // ss2
#pragma unroll 1
    for (int j=0;j<8;++j) {
        const float b = es[j]*C2_SS;
#pragma unroll 1
        for (int i=0;i<16;++i)
            fma48(hs, MT(i)*b, (const float4*)&wss[(i*8+j)*48]);
    }
    // vvs2
#pragma unroll 1
    for (int j=0;j<8;++j) {
        const float bx=ev[3*j], by=ev[3*j+1], bz=ev[3*j+2];
#pragma unroll 1
        for (int i=0;i<8;++i) {
            const float d = fmaf(MT(16+3*i),bx,fmaf(MT(16+3*i+1),by,MT(16+3*i+2)*bz))*C_UNI;
            fma48(hs, d, (const float4*)&wvvs[(i*8+j)*48]);
        }
    }
    // sv2
#pragma unroll 1
    for (int j=0;j<8;++j) {
        float t[16];
#pragma unroll
        for (int k=0;k<16;++k) t[k]=0.f;
#pragma unroll 2
        for (int i=0;i<16;++i)
            fma16(t, MT(i), (const float4*)&wsv[(i*8+j)*16]);
        const float bx=ev[3*j]*C_UNI, by=ev[3*j+1]*C_UNI, bz=ev[3*j+2]*C_UNI;
#pragma unroll
        for (int k=0;k<16;++k){ hvx[k]=fmaf(t[k],bx,hvx[k]); hvy[k]=fmaf(t[k],by,hvy[k]); hvz[k]=fmaf(t[k],bz,hvz[k]); }
    }
    // vs2
#pragma unroll 1
    for (int i=0;i<8;++i) {
        float t[16];
#pragma unroll
        for (int k=0;k<16;++k) t[k]=0.f;
#pragma unroll 2
        for (int j=0;j<8;++j)
            fma16(t, es[j], (const float4*)&wvs[(i*8+j)*16]);
        const float ax=MT(16+3*i)*C2_VS, ay=MT(16+3*i+1)*C2_VS, az=MT(16+3*i+2)*C2_VS;
#pragma unroll
        for (int k=0;k<16;++k){ hvx[k]=fmaf(t[k],ax,hvx[k]); hvy[k]=fmaf(t[k],ay,hvy[k]); hvz[k]=fmaf(t[k],az,hvz[k]); }
    }
    // vvv2
#pragma unroll 1
    for (int j=0;j<8;++j) {
        const float bx=ev[3*j], by=ev[3*j+1], bz=ev[3*j+2];
#pragma unroll 1
        for (int i=0;i<8;++i) {
            const float ax=MT(16+3*i), ay=MT(16+3*i+1), az=MT(16+3*i+2);
            const float cx=(ay*bz-az*by)*C_UNI, cy=(az*bx-ax*bz)*C_UNI, cz=(ax*by-ay*bx)*C_UNI;
            vfma16(hvx,hvy,hvz, cx,cy,cz, (const float4*)&wvvv[(i*8+j)*16]);
        }
    }
#undef MT
    // gate + linear
    float os[16];
#pragma unroll
    for (int k=0;k<16;++k) os[k]=0.f;
    float ovx[8],ovy[8],ovz[8];
#pragma unroll
    for (int k=0;k<8;++k){ ovx[k]=0.f; ovy[k]=0.f; ovz[k]=0.f; }
#pragma unroll
    for (int i=0;i<32;++i) {
        const float x = hs[i];
        const float a = x/(1.f+__expf(-x))*C_LS;
        fma16(os, a, (const float4*)&lms[i*16]);
    }
#pragma unroll
    for (int i=0;i<16;++i) {
        const float g = C_LV/(1.f+__expf(-hs[32+i]));
        vfma8(ovx,ovy,ovz, hvx[i]*g, hvy[i]*g, hvz[i]*g, (const float4*)&lmv[i*8]);
    }
    // scatter into transposed agg
#pragma unroll
    for (int k=0;k<16;++k) atomicAdd(&agg_t[(size_t)k*N+col], os[k]);
#pragma unroll
    for (int k=0;k<8;++k) {
        atomicAdd(&agg_t[(size_t)(16+3*k+0)*N+col], ovx[k]);
        atomicAdd(&agg_t[(size_t)(16+3*k+1)*N+col], ovy[k]);
        atomicAdd(&agg_t[(size_t)(16+3*k+2)*N+col], ovz[k]);
    }
}

// =====================================================================
// K3: update TP(node, agg) -> gate -> linear -> out[N,40]
// LDS: W3ss + W3vvs (60 KB); small paths read global (uniform, L1/L2-hot).
// =====================================================================
__global__ __launch_bounds__(256)
void node_upd(const float* __restrict__ node_s, const float* __restrict__ node_v,
              const float* __restrict__ agg_t,
              const float* __restrict__ gW3ss, const float* __restrict__ gW3sv,
              const float* __restrict__ gW3vs, const float* __restrict__ gW3vvs,
              const float* __restrict__ gW3vvv,
              const float* __restrict__ Lus, const float* __restrict__ Luv,
              float* __restrict__ out, int N)
{
    __shared__ __align__(16) float wss[12288], wvvs[3072];
    const int tid = threadIdx.x;
    {
        float4* d; const float4* s;
        d=(float4*)wss;  s=(const float4*)gW3ss;  for(int i=tid;i<3072;i+=256) d[i]=s[i];
        d=(float4*)wvvs; s=(const float4*)gW3vvs; for(int i=tid;i<768; i+=256) d[i]=s[i];
    }
    __syncthreads();
    const int n = blockIdx.x*256 + tid;
    if (n >= N) return;
    const float* rs = node_s + (size_t)n*16;
    const float* rv = node_v + (size_t)n*24;
#define AS(j)   agg_t[(size_t)(j)*N + n]
#define AV(j,c) agg_t[(size_t)(16+3*(j)+(c))*N + n]

    float hs[48];
#pragma unroll
    for (int k=0;k<48;++k) hs[k]=0.f;
    float hvx[16],hvy[16],hvz[16];
#pragma unroll
    for (int k=0;k<16;++k){ hvx[k]=0.f; hvy[k]=0.f; hvz[k]=0.f; }

    // ss3
#pragma unroll 1
    for (int i=0;i<16;++i) {
        const float a = rs[i]*C_SS16;
#pragma unroll 1
        for (int j=0;j<16;++j)
            fma48(hs, a*AS(j), (const float4*)&wss[(i*16+j)*48]);
    }
    // vvs3
#pragma unroll 1
    for (int i=0;i<8;++i) {
        const float ax=rv[3*i], ay=rv[3*i+1], az=rv[3*i+2];
#pragma unroll 1
        for (int j=0;j<8;++j) {
            const float d = fmaf(ax,AV(j,0),fmaf(ay,AV(j,1),az*AV(j,2)))*C_UNI;
            fma48(hs, d, (const float4*)&wvvs[(i*8+j)*48]);
        }
    }
    // sv3 (global weights, wave-uniform addresses)
#pragma unroll 1
    for (int j=0;j<8;++j) {
        float t[16];
#pragma unroll
        for (int k=0;k<16;++k) t[k]=0.f;
#pragma unroll 2
        for (int i=0;i<16;++i)
            fma16(t, rs[i], (const float4*)&gW3sv[(i*8+j)*16]);
        const float bx=AV(j,0)*C_UNI, by=AV(j,1)*C_UNI, bz=AV(j,2)*C_UNI;
#pragma unroll
        for (int k=0;k<16;++k){ hvx[k]=fmaf(t[k],bx,hvx[k]); hvy[k]=fmaf(t[k],by,hvy[k]); hvz[k]=fmaf(t[k],bz,hvz[k]); }
    }
    // vs3
#pragma unroll 1
    for (int i=0;i<8;++i) {
        float t[16];
#pragma unroll
        for (int k=0;k<16;++k) t[k]=0.f;
#pragma unroll 2
        for (int j=0;j<16;++j)
            fma16(t, AS(j), (const float4*)&gW3vs[(i*16+j)*16]);
        const float ax=rv[3*i]*C_UNI, ay=rv[3*i+1]*C_UNI, az=rv[3*i+2]*C_UNI;
#pragma unroll
        for (int k=0;k<16;++k){ hvx[k]=fmaf(t[k],ax,hvx[k]); hvy[k]=fmaf(t[k],ay,hvy[k]); hvz[k]=fmaf(t[k],az,hvz[k]); }
    }
    // vvv3
#pragma unroll 1
    for (int i=0;i<8;++i) {
        const float ax=rv[3*i], ay=rv[3*i+1], az=rv[3*i+2];
#pragma unroll 1
        for (int j=0;j<8;++j) {
            const float bx=AV(j,0), by=AV(j,1), bz=AV(j,2);
            const float cx=(ay*bz-az*by)*C_UNI, cy=(az*bx-ax*bz)*C_UNI, cz=(ax*by-ay*bx)*C_UNI;
            vfma16(hvx,hvy,hvz, cx,cy,cz, (const float4*)&gW3vvv[(i*8+j)*16]);
        }
    }
#undef AS
#undef AV
    // gate + linear
    float os[16];
#pragma unroll
    for (int k=0;k<16;++k) os[k]=0.f;
    float ovx[8],ovy[8],ovz[8];
#pragma unroll
    for (int k=0;k<8;++k){ ovx[k]=0.f; ovy[k]=0.f; ovz[k]=0.f; }
#pragma unroll
    for (int i=0;i<32;++i) {
        const float x = hs[i];
        const float a = x/(1.f+__expf(-x))*C_LS;
        fma16(os, a, (const float4*)&Lus[i*16]);
    }
#pragma unroll
    for (int i=0;i<16;++i) {
        const float g = C_LV/(1.f+__expf(-hs[32+i]));
        vfma8(ovx,ovy,ovz, hvx[i]*g, hvy[i]*g, hvz[i]*g, (const float4*)&Luv[i*8]);
    }
    float ob[40];
#pragma unroll
    for (int k=0;k<16;++k) ob[k]=os[k];
#pragma unroll
    for (int k=0;k<8;++k) {
        ob[16+3*k]=ovx[k]; ob[16+3*k+1]=ovy[k]; ob[16+3*k+2]=ovz[k];
    }
    float4* o4 = (float4*)(out + (size_t)n*40);
#pragma unroll
    for (int q=0;q<10;++q) o4[q]=make_float4(ob[4*q],ob[4*q+1],ob[4*q+2],ob[4*q+3]);
}

// =====================================================================
extern "C" void kernel_launch(void* const* d_in, const int* in_sizes, int n_in,
                              void* d_out, int out_size, void* d_ws, size_t ws_size,
                              hipStream_t stream) {
    const float* node_s = (const float*)d_in[0];
    const float* node_v = (const float*)d_in[1];
    const float* edge_s = (const float*)d_in[3];
    const float* edge_v = (const float*)d_in[4];
    const int*   ei     = (const int*)d_in[5];
    const float* W1ss = (const float*)d_in[6];
    const float* W1sv = (const float*)d_in[7];
    const float* W1vs = (const float*)d_in[8];
    const float* W1vvs= (const float*)d_in[9];
    const float* W1vvv= (const float*)d_in[10];
    const float* W2ss = (const float*)d_in[11];
    const float* W2sv = (const float*)d_in[12];
    const float* W2vs = (const float*)d_in[13];
    const float* W2vvs= (const float*)d_in[14];
    const float* W2vvv= (const float*)d_in[15];
    const float* Lms  = (const float*)d_in[16];
    const float* Lmv  = (const float*)d_in[17];
    const float* W3ss = (const float*)d_in[18];
    const float* W3sv = (const float*)d_in[19];
    const float* W3vs = (const float*)d_in[20];
    const float* W3vvs= (const float*)d_in[21];
    const float* W3vvv= (const float*)d_in[22];
    const float* Lus  = (const float*)d_in[23];
    const float* Luv  = (const float*)d_in[24];

    float* out = (float*)d_out;
    const int N = in_sizes[0] / 16;
    const int E = in_sizes[5] / 2;

    float* agg_t = (float*)d_ws;                 // [40][N]  (8 MB)
    float* m_t   = agg_t + (size_t)40 * N;       // [40][E]  (64 MB)

    hipMemsetAsync(agg_t, 0, (size_t)40 * N * sizeof(float), stream);

    edge_tp1<<<(E + 127) / 128, 128, 0, stream>>>(
        node_s, node_v, ei, W1ss, W1sv, W1vs, W1vvs, W1vvv, m_t, E);

    edge_tp2<<<(E + 255) / 256, 256, 0, stream>>>(
        m_t, edge_s, edge_v, ei,
        W2ss, W2sv, W2vs, W2vvs, W2vvv, Lms, Lmv, agg_t, E, N);

    node_upd<<<(N + 255) / 256, 256, 0, stream>>>(
        node_s, node_v, agg_t,
        W3ss, W3sv, W3vs, W3vvs, W3vvv, Lus, Luv, out, N);
}

// Round 3
// 1408.728 us; speedup vs baseline: 1.8598x; 1.0554x over previous
//
#include <hip/hip_runtime.h>
#include <math.h>

// node: 16x0e + 8x1o ; edge: 8x0e + 8x1o ; hidden: 48 scalars (32 silu + 16 gate), 16 vec
// output: 16x0e + 8x1o -> [N, 40]

constexpr float C_SS16 = 0.04419417382415922f;  // i2/16
constexpr float C_UNI  = 0.05103103630798288f;  // i3/sqrt(128)
constexpr float C2_SS  = 0.0625f;               // i2/sqrt(128)
constexpr float C2_VS  = 0.07216878364870323f;  // i3/8
constexpr float C_LS   = 0.17677669529663687f;  // 1/sqrt(32)
constexpr float C_LV   = 0.25f;                 // 1/sqrt(16)

// ---- acc[0:K] += p * w[0:K]; w from GLOBAL with wave-uniform address (-> s_load) ----
__device__ __forceinline__ void fma8(float* acc, float p, const float4* __restrict__ w4) {
#pragma unroll
    for (int kk = 0; kk < 2; ++kk) {
        float4 w = w4[kk];
        acc[4*kk+0] = fmaf(p, w.x, acc[4*kk+0]);
        acc[4*kk+1] = fmaf(p, w.y, acc[4*kk+1]);
        acc[4*kk+2] = fmaf(p, w.z, acc[4*kk+2]);
        acc[4*kk+3] = fmaf(p, w.w, acc[4*kk+3]);
    }
}
__device__ __forceinline__ void fma16(float* acc, float p, const float4* __restrict__ w4) {
#pragma unroll
    for (int kk = 0; kk < 4; ++kk) {
        float4 w = w4[kk];
        acc[4*kk+0] = fmaf(p, w.x, acc[4*kk+0]);
        acc[4*kk+1] = fmaf(p, w.y, acc[4*kk+1]);
        acc[4*kk+2] = fmaf(p, w.z, acc[4*kk+2]);
        acc[4*kk+3] = fmaf(p, w.w, acc[4*kk+3]);
    }
}
__device__ __forceinline__ void fma48(float* acc, float p, const float4* __restrict__ w4) {
#pragma unroll
    for (int kk = 0; kk < 12; ++kk) {
        float4 w = w4[kk];
        acc[4*kk+0] = fmaf(p, w.x, acc[4*kk+0]);
        acc[4*kk+1] = fmaf(p, w.y, acc[4*kk+1]);
        acc[4*kk+2] = fmaf(p, w.z, acc[4*kk+2]);
        acc[4*kk+3] = fmaf(p, w.w, acc[4*kk+3]);
    }
}
__device__ __forceinline__ void vfma8(float* ax_, float* ay_, float* az_,
                                      float cx, float cy, float cz, const float4* __restrict__ w4) {
#pragma unroll
    for (int kk = 0; kk < 2; ++kk) {
        float4 w = w4[kk];
        ax_[4*kk+0]=fmaf(cx,w.x,ax_[4*kk+0]); ay_[4*kk+0]=fmaf(cy,w.x,ay_[4*kk+0]); az_[4*kk+0]=fmaf(cz,w.x,az_[4*kk+0]);
        ax_[4*kk+1]=fmaf(cx,w.y,ax_[4*kk+1]); ay_[4*kk+1]=fmaf(cy,w.y,ay_[4*kk+1]); az_[4*kk+1]=fmaf(cz,w.y,az_[4*kk+1]);
        ax_[4*kk+2]=fmaf(cx,w.z,ax_[4*kk+2]); ay_[4*kk+2]=fmaf(cy,w.z,ay_[4*kk+2]); az_[4*kk+2]=fmaf(cz,w.z,az_[4*kk+2]);
        ax_[4*kk+3]=fmaf(cx,w.w,ax_[4*kk+3]); ay_[4*kk+3]=fmaf(cy,w.w,ay_[4*kk+3]); az_[4*kk+3]=fmaf(cz,w.w,az_[4*kk+3]);
    }
}
__device__ __forceinline__ void vfma16(float* ax_, float* ay_, float* az_,
                                       float cx, float cy, float cz, const float4* __restrict__ w4) {
#pragma unroll
    for (int kk = 0; kk < 4; ++kk) {
        float4 w = w4[kk];
        ax_[4*kk+0]=fmaf(cx,w.x,ax_[4*kk+0]); ay_[4*kk+0]=fmaf(cy,w.x,ay_[4*kk+0]); az_[4*kk+0]=fmaf(cz,w.x,az_[4*kk+0]);
        ax_[4*kk+1]=fmaf(cx,w.y,ax_[4*kk+1]); ay_[4*kk+1]=fmaf(cy,w.y,ay_[4*kk+1]); az_[4*kk+1]=fmaf(cz,w.y,az_[4*kk+1]);
        ax_[4*kk+2]=fmaf(cx,w.z,ax_[4*kk+2]); ay_[4*kk+2]=fmaf(cy,w.z,ay_[4*kk+2]); az_[4*kk+2]=fmaf(cz,w.z,az_[4*kk+2]);
        ax_[4*kk+3]=fmaf(cx,w.w,ax_[4*kk+3]); ay_[4*kk+3]=fmaf(cy,w.w,ay_[4*kk+3]); az_[4*kk+3]=fmaf(cz,w.w,az_[4*kk+3]);
    }
}

// =====================================================================
// K1: stage-1 TP(node[row], node[col]) -> m_t[40][E]
// LDS: per-thread feature scratch only, feature-major (conflict-free).
// Rolled loop indices read LDS; unrolled indices read registers.
// =====================================================================
__global__ __launch_bounds__(256)
void edge_tp1(const float* __restrict__ node_s, const float* __restrict__ node_v,
              const int* __restrict__ ei,
              const float* __restrict__ gW1ss, const float* __restrict__ gW1sv,
              const float* __restrict__ gW1vs, const float* __restrict__ gW1vvs,
              const float* __restrict__ gW1vvv,
              float* __restrict__ m_t, int E)
{
    extern __shared__ float lds[];   // [40][256]: rs[16] | rvx[8] rvy[8] rvz[8]
    const int tid = threadIdx.x;
    const int e = blockIdx.x * 256 + tid;
    if (e >= E) return;
    const int row = ei[e], col = ei[E + e];
#define Lrs(i)  lds[(i)*256 + tid]
#define Lrvx(i) lds[(16+(i))*256 + tid]
#define Lrvy(i) lds[(24+(i))*256 + tid]
#define Lrvz(i) lds[(32+(i))*256 + tid]
    {   // row features -> LDS (dynamic-indexed later)
        const float4* p = (const float4*)(node_s + (size_t)row * 16);
#pragma unroll
        for (int q=0;q<4;++q){ float4 t=p[q]; Lrs(4*q)=t.x; Lrs(4*q+1)=t.y; Lrs(4*q+2)=t.z; Lrs(4*q+3)=t.w; }
        const float4* pv = (const float4*)(node_v + (size_t)row * 24);
        float tmp[24];
#pragma unroll
        for (int q=0;q<6;++q){ float4 t=pv[q]; tmp[4*q]=t.x; tmp[4*q+1]=t.y; tmp[4*q+2]=t.z; tmp[4*q+3]=t.w; }
#pragma unroll
        for (int k=0;k<8;++k){ Lrvx(k)=tmp[3*k]; Lrvy(k)=tmp[3*k+1]; Lrvz(k)=tmp[3*k+2]; }
    }
    // col features -> registers (static-indexed only)
    float cs[16], cvx[8], cvy[8], cvz[8];
    {
        const float4* p = (const float4*)(node_s + (size_t)col * 16);
#pragma unroll
        for (int q=0;q<4;++q){ float4 t=p[q]; cs[4*q]=t.x; cs[4*q+1]=t.y; cs[4*q+2]=t.z; cs[4*q+3]=t.w; }
        const float4* pv = (const float4*)(node_v + (size_t)col * 24);
        float tmp[24];
#pragma unroll
        for (int q=0;q<6;++q){ float4 t=pv[q]; tmp[4*q]=t.x; tmp[4*q+1]=t.y; tmp[4*q+2]=t.z; tmp[4*q+3]=t.w; }
#pragma unroll
        for (int k=0;k<8;++k){ cvx[k]=tmp[3*k]; cvy[k]=tmp[3*k+1]; cvz[k]=tmp[3*k+2]; }
    }

    float ms[16];
#pragma unroll
    for (int k=0;k<16;++k) ms[k]=0.f;
    float mvx[8], mvy[8], mvz[8];
#pragma unroll
    for (int k=0;k<8;++k){ mvx[k]=0.f; mvy[k]=0.f; mvz[k]=0.f; }

    // ss1: roll i (Lrs), unroll j (cs regs)
#pragma unroll 1
    for (int i=0;i<16;++i) {
        const float a = Lrs(i) * C_SS16;
#pragma unroll
        for (int j=0;j<16;++j)
            fma16(ms, a*cs[j], (const float4*)&gW1ss[(i*16+j)*16]);
    }
    // vvs1: roll i (Lrv), unroll j (cv regs)
#pragma unroll 1
    for (int i=0;i<8;++i) {
        const float ax=Lrvx(i), ay=Lrvy(i), az=Lrvz(i);
#pragma unroll
        for (int j=0;j<8;++j) {
            const float d = fmaf(ax,cvx[j],fmaf(ay,cvy[j],az*cvz[j]))*C_UNI;
            fma16(ms, d, (const float4*)&gW1vvs[(i*8+j)*16]);
        }
    }
    // sv1: unroll j; per-j t[8] via rolled i (Lrs); outer product with cv regs
#pragma unroll
    for (int j=0;j<8;++j) {
        float t[8];
#pragma unroll
        for (int k=0;k<8;++k) t[k]=0.f;
#pragma unroll 1
        for (int i=0;i<16;++i)
            fma8(t, Lrs(i), (const float4*)&gW1sv[(i*8+j)*8]);
        const float bx=cvx[j]*C_UNI, by=cvy[j]*C_UNI, bz=cvz[j]*C_UNI;
#pragma unroll
        for (int k=0;k<8;++k){ mvx[k]=fmaf(t[k],bx,mvx[k]); mvy[k]=fmaf(t[k],by,mvy[k]); mvz[k]=fmaf(t[k],bz,mvz[k]); }
    }
    // vs1: roll i (Lrv); per-i t[8] via unrolled j (cs regs)
#pragma unroll 1
    for (int i=0;i<8;++i) {
        float t[8];
#pragma unroll
        for (int k=0;k<8;++k) t[k]=0.f;
#pragma unroll
        for (int j=0;j<16;++j)
            fma8(t, cs[j], (const float4*)&gW1vs[(i*16+j)*8]);
        const float ax=Lrvx(i)*C_UNI, ay=Lrvy(i)*C_UNI, az=Lrvz(i)*C_UNI;
#pragma unroll
        for (int k=0;k<8;++k){ mvx[k]=fmaf(t[k],ax,mvx[k]); mvy[k]=fmaf(t[k],ay,mvy[k]); mvz[k]=fmaf(t[k],az,mvz[k]); }
    }
    // vvv1: roll i (Lrv), unroll j (cv regs)
#pragma unroll 1
    for (int i=0;i<8;++i) {
        const float ax=Lrvx(i), ay=Lrvy(i), az=Lrvz(i);
#pragma unroll
        for (int j=0;j<8;++j) {
            const float bx=cvx[j], by=cvy[j], bz=cvz[j];
            const float cx=(ay*bz-az*by)*C_UNI, cy=(az*bx-ax*bz)*C_UNI, cz=(ax*by-ay*bx)*C_UNI;
            vfma8(mvx,mvy,mvz, cx,cy,cz, (const float4*)&gW1vvv[(i*8+j)*8]);
        }
    }
#undef Lrs
#undef Lrvx
#undef Lrvy
#undef Lrvz
    // store transposed -> coalesced in K2
#pragma unroll
    for (int k=0;k<16;++k) m_t[(size_t)k*E + e] = ms[k];
#pragma unroll
    for (int k=0;k<8;++k) {
        m_t[(size_t)(16+3*k+0)*E + e] = mvx[k];
        m_t[(size_t)(16+3*k+1)*E + e] = mvy[k];
        m_t[(size_t)(16+3*k+2)*E + e] = mvz[k];
    }
}

// =====================================================================
// K2: stage-2 TP(m, edge_attr) -> gate -> linear -> atomic scatter agg_t[40][N]
// Phase A: hs[48] -> scalar outputs + gates; Phase B: hv[48] -> vector outputs.
// =====================================================================
__global__ __launch_bounds__(256)
void edge_tp2(const float* __restrict__ m_t,
              const float* __restrict__ edge_s, const float* __restrict__ edge_v,
              const int* __restrict__ ei,
              const float* __restrict__ gW2ss, const float* __restrict__ gW2sv,
              const float* __restrict__ gW2vs, const float* __restrict__ gW2vvs,
              const float* __restrict__ gW2vvv,
              const float* __restrict__ gLms, const float* __restrict__ gLmv,
              float* __restrict__ agg_t, int E, int N)
{
    extern __shared__ float lds[];   // [40][256]: ms[16] | mvx[8] mvy[8] mvz[8]
    const int tid = threadIdx.x;
    const int e = blockIdx.x*256 + tid;
    if (e >= E) return;
    const int col = ei[E+e];
#define Lms(i)  lds[(i)*256 + tid]
#define Lmvx(i) lds[(16+(i))*256 + tid]
#define Lmvy(i) lds[(24+(i))*256 + tid]
#define Lmvz(i) lds[(32+(i))*256 + tid]
    // m from m_t (coalesced) -> LDS scratch
#pragma unroll
    for (int f=0; f<16; ++f) Lms(f) = m_t[(size_t)f*E + e];
#pragma unroll
    for (int k=0; k<8; ++k) {
        Lmvx(k) = m_t[(size_t)(16+3*k+0)*E + e];
        Lmvy(k) = m_t[(size_t)(16+3*k+1)*E + e];
        Lmvz(k) = m_t[(size_t)(16+3*k+2)*E + e];
    }
    // edge attrs -> registers (static use only)
    float es[8], evx[8], evy[8], evz[8];
    {
        const float4* p = (const float4*)(edge_s + (size_t)e*8);
#pragma unroll
        for (int q=0;q<2;++q){ float4 t=p[q]; es[4*q]=t.x; es[4*q+1]=t.y; es[4*q+2]=t.z; es[4*q+3]=t.w; }
        const float4* pv = (const float4*)(edge_v + (size_t)e*24);
        float tmp[24];
#pragma unroll
        for (int q=0;q<6;++q){ float4 t=pv[q]; tmp[4*q]=t.x; tmp[4*q+1]=t.y; tmp[4*q+2]=t.z; tmp[4*q+3]=t.w; }
#pragma unroll
        for (int k=0;k<8;++k){ evx[k]=tmp[3*k]; evy[k]=tmp[3*k+1]; evz[k]=tmp[3*k+2]; }
    }

    // ---------- Phase A: scalar channels hs[48] ----------
    float g[16];
    {
        float hs[48];
#pragma unroll
        for (int k=0;k<48;++k) hs[k]=0.f;
        // ss2: roll i (Lms), unroll j (es regs)
#pragma unroll 1
        for (int i=0;i<16;++i) {
            const float a = Lms(i)*C2_SS;
#pragma unroll
            for (int j=0;j<8;++j)
                fma48(hs, a*es[j], (const float4*)&gW2ss[(i*8+j)*48]);
        }
        // vvs2: roll i (Lmv), unroll j (ev regs)
#pragma unroll 1
        for (int i=0;i<8;++i) {
            const float ax=Lmvx(i), ay=Lmvy(i), az=Lmvz(i);
#pragma unroll
            for (int j=0;j<8;++j) {
                const float d = fmaf(ax,evx[j],fmaf(ay,evy[j],az*evz[j]))*C_UNI;
                fma48(hs, d, (const float4*)&gW2vvs[(i*8+j)*48]);
            }
        }
        // silu + Lms -> scalar outputs, scatter
        float os[16];
#pragma unroll
        for (int k=0;k<16;++k) os[k]=0.f;
#pragma unroll
        for (int i=0;i<32;++i) {
            const float x = hs[i];
            const float a = x/(1.f+__expf(-x))*C_LS;
            fma16(os, a, (const float4*)&gLms[i*16]);
        }
        float* dsts = agg_t + col;
#pragma unroll
        for (int k=0;k<16;++k) atomicAdd(dsts + (size_t)k*N, os[k]);
        // gates for phase B
#pragma unroll
        for (int i=0;i<16;++i) g[i] = C_LV/(1.f+__expf(-hs[32+i]));
    }

    // ---------- Phase B: vector channels hv[16][3] ----------
    float hvx[16],hvy[16],hvz[16];
#pragma unroll
    for (int k=0;k<16;++k){ hvx[k]=0.f; hvy[k]=0.f; hvz[k]=0.f; }
    // sv2: unroll j; per-j t[16] via rolled i (Lms); outer with ev regs
#pragma unroll
    for (int j=0;j<8;++j) {
        float t[16];
#pragma unroll
        for (int k=0;k<16;++k) t[k]=0.f;
#pragma unroll 1
        for (int i=0;i<16;++i)
            fma16(t, Lms(i), (const float4*)&gW2sv[(i*8+j)*16]);
        const float bx=evx[j]*C_UNI, by=evy[j]*C_UNI, bz=evz[j]*C_UNI;
#pragma unroll
        for (int k=0;k<16;++k){ hvx[k]=fmaf(t[k],bx,hvx[k]); hvy[k]=fmaf(t[k],by,hvy[k]); hvz[k]=fmaf(t[k],bz,hvz[k]); }
    }
    // vs2: roll i (Lmv); per-i t[16] via unrolled j (es regs)
#pragma unroll 1
    for (int i=0;i<8;++i) {
        float t[16];
#pragma unroll
        for (int k=0;k<16;++k) t[k]=0.f;
#pragma unroll
        for (int j=0;j<8;++j)
            fma16(t, es[j], (const float4*)&gW2vs[(i*8+j)*16]);
        const float ax=Lmvx(i)*C2_VS, ay=Lmvy(i)*C2_VS, az=Lmvz(i)*C2_VS;
#pragma unroll
        for (int k=0;k<16;++k){ hvx[k]=fmaf(t[k],ax,hvx[k]); hvy[k]=fmaf(t[k],ay,hvy[k]); hvz[k]=fmaf(t[k],az,hvz[k]); }
    }
    // vvv2: roll i (Lmv), unroll j (ev regs)
#pragma unroll 1
    for (int i=0;i<8;++i) {
        const float ax=Lmvx(i), ay=Lmvy(i), az=Lmvz(i);
#pragma unroll
        for (int j=0;j<8;++j) {
            const float bx=evx[j], by=evy[j], bz=evz[j];
            const float cx=(ay*bz-az*by)*C_UNI, cy=(az*bx-ax*bz)*C_UNI, cz=(ax*by-ay*bx)*C_UNI;
            vfma16(hvx,hvy,hvz, cx,cy,cz, (const float4*)&gW2vvv[(i*8+j)*16]);
        }
    }
#undef Lms
#undef Lmvx
#undef Lmvy
#undef Lmvz
    // gate + Lmv, scatter vectors
    float ovx[8],ovy[8],ovz[8];
#pragma unroll
    for (int k=0;k<8;++k){ ovx[k]=0.f; ovy[k]=0.f; ovz[k]=0.f; }
#pragma unroll
    for (int i=0;i<16;++i)
        vfma8(ovx,ovy,ovz, hvx[i]*g[i], hvy[i]*g[i], hvz[i]*g[i], (const float4*)&gLmv[i*8]);
    float* dstv = agg_t + col;
#pragma unroll
    for (int k=0;k<8;++k) {
        atomicAdd(dstv + (size_t)(16+3*k+0)*N, ovx[k]);
        atomicAdd(dstv + (size_t)(16+3*k+1)*N, ovy[k]);
        atomicAdd(dstv + (size_t)(16+3*k+2)*N, ovz[k]);
    }
}

// =====================================================================
// K3: update TP(node, agg) -> gate -> linear -> out[N,40]
// =====================================================================
__global__ __launch_bounds__(256)
void node_upd(const float* __restrict__ node_s, const float* __restrict__ node_v,
              const float* __restrict__ agg_t,
              const float* __restrict__ gW3ss, const float* __restrict__ gW3sv,
              const float* __restrict__ gW3vs, const float* __restrict__ gW3vvs,
              const float* __restrict__ gW3vvv,
              const float* __restrict__ gLus, const float* __restrict__ gLuv,
              float* __restrict__ out, int N)
{
    extern __shared__ float lds[];   // [40][256]: rs[16] | rvx rvy rvz
    const int tid = threadIdx.x;
    const int n = blockIdx.x*256 + tid;
    if (n >= N) return;
#define Lrs(i)  lds[(i)*256 + tid]
#define Lrvx(i) lds[(16+(i))*256 + tid]
#define Lrvy(i) lds[(24+(i))*256 + tid]
#define Lrvz(i) lds[(32+(i))*256 + tid]
    {
        const float4* p = (const float4*)(node_s + (size_t)n*16);
#pragma unroll
        for (int q=0;q<4;++q){ float4 t=p[q]; Lrs(4*q)=t.x; Lrs(4*q+1)=t.y; Lrs(4*q+2)=t.z; Lrs(4*q+3)=t.w; }
        const float4* pv = (const float4*)(node_v + (size_t)n*24);
        float tmp[24];
#pragma unroll
        for (int q=0;q<6;++q){ float4 t=pv[q]; tmp[4*q]=t.x; tmp[4*q+1]=t.y; tmp[4*q+2]=t.z; tmp[4*q+3]=t.w; }
#pragma unroll
        for (int k=0;k<8;++k){ Lrvx(k)=tmp[3*k]; Lrvy(k)=tmp[3*k+1]; Lrvz(k)=tmp[3*k+2]; }
    }
    // aggregated features -> registers (coalesced loads, static use)
    float as_[16], avx[8], avy[8], avz[8];
#pragma unroll
    for (int j=0;j<16;++j) as_[j] = agg_t[(size_t)j*N + n];
#pragma unroll
    for (int j=0;j<8;++j) {
        avx[j] = agg_t[(size_t)(16+3*j+0)*N + n];
        avy[j] = agg_t[(size_t)(16+3*j+1)*N + n];
        avz[j] = agg_t[(size_t)(16+3*j+2)*N + n];
    }

    // ---------- Phase A: hs[48] ----------
    float g[16];
    {
        float hs[48];
#pragma unroll
        for (int k=0;k<48;++k) hs[k]=0.f;
        // ss3: roll i (Lrs), unroll j (as regs)
#pragma unroll 1
        for (int i=0;i<16;++i) {
            const float a = Lrs(i)*C_SS16;
#pragma unroll
            for (int j=0;j<16;++j)
                fma48(hs, a*as_[j], (const float4*)&gW3ss[(i*16+j)*48]);
        }
        // vvs3: roll i (Lrv), unroll j (av regs)
#pragma unroll 1
        for (int i=0;i<8;++i) {
            const float ax=Lrvx(i), ay=Lrvy(i), az=Lrvz(i);
#pragma unroll
            for (int j=0;j<8;++j) {
                const float d = fmaf(ax,avx[j],fmaf(ay,avy[j],az*avz[j]))*C_UNI;
                fma48(hs, d, (const float4*)&gW3vvs[(i*8+j)*48]);
            }
        }
        float os[16];
#pragma unroll
        for (int k=0;k<16;++k) os[k]=0.f;
#pragma unroll
        for (int i=0;i<32;++i) {
            const float x = hs[i];
            const float a = x/(1.f+__expf(-x))*C_LS;
            fma16(os, a, (const float4*)&gLus[i*16]);
        }
        // write scalar part of output now
        float4* o4 = (float4*)(out + (size_t)n*40);
#pragma unroll
        for (int q=0;q<4;++q) o4[q] = make_float4(os[4*q],os[4*q+1],os[4*q+2],os[4*q+3]);
#pragma unroll
        for (int i=0;i<16;++i) g[i] = C_LV/(1.f+__expf(-hs[32+i]));
    }

    // ---------- Phase B: hv[16][3] ----------
    float hvx[16],hvy[16],hvz[16];
#pragma unroll
    for (int k=0;k<16;++k){ hvx[k]=0.f; hvy[k]=0.f; hvz[k]=0.f; }
    // sv3: unroll j; per-j t[16] via rolled i (Lrs); outer with av regs
#pragma unroll
    for (int j=0;j<8;++j) {
        float t[16];
#pragma unroll
        for (int k=0;k<16;++k) t[k]=0.f;
#pragma unroll 1
        for (int i=0;i<16;++i)
            fma16(t, Lrs(i), (const float4*)&gW3sv[(i*8+j)*16]);
        const float bx=avx[j]*C_UNI, by=avy[j]*C_UNI, bz=avz[j]*C_UNI;
#pragma unroll
        for (int k=0;k<16;++k){ hvx[k]=fmaf(t[k],bx,hvx[k]); hvy[k]=fmaf(t[k],by,hvy[k]); hvz[k]=fmaf(t[k],bz,hvz[k]); }
    }
    // vs3: roll i (Lrv); per-i t[16] via unrolled j (as regs)
#pragma unroll 1
    for (int i=0;i<8;++i) {
        float t[16];
#pragma unroll
        for (int k=0;k<16;++k) t[k]=0.f;
#pragma unroll
        for (int j=0;j<16;++j)
            fma16(t, as_[j], (const float4*)&gW3vs[(i*16+j)*16]);
        const float ax=Lrvx(i)*C_UNI, ay=Lrvy(i)*C_UNI, az=Lrvz(i)*C_UNI;
#pragma unroll
        for (int k=0;k<16;++k){ hvx[k]=fmaf(t[k],ax,hvx[k]); hvy[k]=fmaf(t[k],ay,hvy[k]); hvz[k]=fmaf(t[k],az,hvz[k]); }
    }
    // vvv3: roll i (Lrv), unroll j (av regs)
#pragma unroll 1
    for (int i=0;i<8;++i) {
        const float ax=Lrvx(i), ay=Lrvy(i), az=Lrvz(i);
#pragma unroll
        for (int j=0;j<8;++j) {
            const float bx=avx[j], by=avy[j], bz=avz[j];
            const float cx=(ay*bz-az*by)*C_UNI, cy=(az*bx-ax*bz)*C_UNI, cz=(ax*by-ay*bx)*C_UNI;
            vfma16(hvx,hvy,hvz, cx,cy,cz, (const float4*)&gW3vvv[(i*8+j)*16]);
        }
    }
#undef Lrs
#undef Lrvx
#undef Lrvy
#undef Lrvz
    float ovx[8],ovy[8],ovz[8];
#pragma unroll
    for (int k=0;k<8;++k){ ovx[k]=0.f; ovy[k]=0.f; ovz[k]=0.f; }
#pragma unroll
    for (int i=0;i<16;++i)
        vfma8(ovx,ovy,ovz, hvx[i]*g[i], hvy[i]*g[i], hvz[i]*g[i], (const float4*)&gLuv[i*8]);
    float ob[24];
#pragma unroll
    for (int k=0;k<8;++k){ ob[3*k]=ovx[k]; ob[3*k+1]=ovy[k]; ob[3*k+2]=ovz[k]; }
    float4* o4 = (float4*)(out + (size_t)n*40 + 16);
#pragma unroll
    for (int q=0;q<6;++q) o4[q]=make_float4(ob[4*q],ob[4*q+1],ob[4*q+2],ob[4*q+3]);
}

// =====================================================================
extern "C" void kernel_launch(void* const* d_in, const int* in_sizes, int n_in,
                              void* d_out, int out_size, void* d_ws, size_t ws_size,
                              hipStream_t stream) {
    const float* node_s = (const float*)d_in[0];
    const float* node_v = (const float*)d_in[1];
    const float* edge_s = (const float*)d_in[3];
    const float* edge_v = (const float*)d_in[4];
    const int*   ei     = (const int*)d_in[5];
    const float* W1ss = (const float*)d_in[6];
    const float* W1sv = (const float*)d_in[7];
    const float* W1vs = (const float*)d_in[8];
    const float* W1vvs= (const float*)d_in[9];
    const float* W1vvv= (const float*)d_in[10];
    const float* W2ss = (const float*)d_in[11];
    const float* W2sv = (const float*)d_in[12];
    const float* W2vs = (const float*)d_in[13];
    const float* W2vvs= (const float*)d_in[14];
    const float* W2vvv= (const float*)d_in[15];
    const float* Lms  = (const float*)d_in[16];
    const float* Lmv  = (const float*)d_in[17];
    const float* W3ss = (const float*)d_in[18];
    const float* W3sv = (const float*)d_in[19];
    const float* W3vs = (const float*)d_in[20];
    const float* W3vvs= (const float*)d_in[21];
    const float* W3vvv= (const float*)d_in[22];
    const float* Lus  = (const float*)d_in[23];
    const float* Luv  = (const float*)d_in[24];

    float* out = (float*)d_out;
    const int N = in_sizes[0] / 16;
    const int E = in_sizes[5] / 2;

    float* agg_t = (float*)d_ws;                 // [40][N]
    float* m_t   = agg_t + (size_t)40 * N;       // [40][E]

    hipMemsetAsync(agg_t, 0, (size_t)40 * N * sizeof(float), stream);

    const size_t shmem = 40 * 256 * sizeof(float);   // 40 KB feature scratch

    edge_tp1<<<(E + 255) / 256, 256, shmem, stream>>>(
        node_s, node_v, ei, W1ss, W1sv, W1vs, W1vvs, W1vvv, m_t, E);

    edge_tp2<<<(E + 255) / 256, 256, shmem, stream>>>(
        m_t, edge_s, edge_v, ei,
        W2ss, W2sv, W2vs, W2vvs, W2vvv, Lms, Lmv, agg_t, E, N);

    node_upd<<<(N + 255) / 256, 256, shmem, stream>>>(
        node_s, node_v, agg_t,
        W3ss, W3sv, W3vs, W3vvs, W3vvv, Lus, Luv, out, N);
}

// Round 6
// 806.090 us; speedup vs baseline: 3.2502x; 1.7476x over previous
//
#include <hip/hip_runtime.h>
#include <math.h>

typedef _Float16 half8 __attribute__((ext_vector_type(8)));
typedef float floatx4 __attribute__((ext_vector_type(4)));

constexpr float C_SS16 = 0.04419417382415922f;  // i2/16
constexpr float C_UNI  = 0.05103103630798288f;  // i3/sqrt(128)
constexpr float C2_SS  = 0.0625f;               // i2/sqrt(128)
constexpr float C2_VS  = 0.07216878364870323f;  // i3/8
constexpr float C_LS   = 0.17677669529663687f;  // 1/sqrt(32)
constexpr float C_LV   = 0.25f;                 // 1/sqrt(16)

// fp32 helpers for node_upd
__device__ __forceinline__ void fma16(float* acc, float p, const float4* __restrict__ w4) {
#pragma unroll
    for (int kk = 0; kk < 4; ++kk) {
        float4 w = w4[kk];
        acc[4*kk+0] = fmaf(p, w.x, acc[4*kk+0]);
        acc[4*kk+1] = fmaf(p, w.y, acc[4*kk+1]);
        acc[4*kk+2] = fmaf(p, w.z, acc[4*kk+2]);
        acc[4*kk+3] = fmaf(p, w.w, acc[4*kk+3]);
    }
}
__device__ __forceinline__ void fma48(float* acc, float p, const float4* __restrict__ w4) {
#pragma unroll
    for (int kk = 0; kk < 12; ++kk) {
        float4 w = w4[kk];
        acc[4*kk+0] = fmaf(p, w.x, acc[4*kk+0]);
        acc[4*kk+1] = fmaf(p, w.y, acc[4*kk+1]);
        acc[4*kk+2] = fmaf(p, w.z, acc[4*kk+2]);
        acc[4*kk+3] = fmaf(p, w.w, acc[4*kk+3]);
    }
}
__device__ __forceinline__ void vfma8(float* ax_, float* ay_, float* az_,
                                      float cx, float cy, float cz, const float4* __restrict__ w4) {
#pragma unroll
    for (int kk = 0; kk < 2; ++kk) {
        float4 w = w4[kk];
        ax_[4*kk+0]=fmaf(cx,w.x,ax_[4*kk+0]); ay_[4*kk+0]=fmaf(cy,w.x,ay_[4*kk+0]); az_[4*kk+0]=fmaf(cz,w.x,az_[4*kk+0]);
        ax_[4*kk+1]=fmaf(cx,w.y,ax_[4*kk+1]); ay_[4*kk+1]=fmaf(cy,w.y,ay_[4*kk+1]); az_[4*kk+1]=fmaf(cz,w.y,az_[4*kk+1]);
        ax_[4*kk+2]=fmaf(cx,w.z,ax_[4*kk+2]); ay_[4*kk+2]=fmaf(cy,w.z,ay_[4*kk+2]); az_[4*kk+2]=fmaf(cz,w.z,az_[4*kk+2]);
        ax_[4*kk+3]=fmaf(cx,w.w,ax_[4*kk+3]); ay_[4*kk+3]=fmaf(cy,w.w,ay_[4*kk+3]); az_[4*kk+3]=fmaf(cz,w.w,az_[4*kk+3]);
    }
}
__device__ __forceinline__ void vfma16(float* ax_, float* ay_, float* az_,
                                       float cx, float cy, float cz, const float4* __restrict__ w4) {
#pragma unroll
    for (int kk = 0; kk < 4; ++kk) {
        float4 w = w4[kk];
        ax_[4*kk+0]=fmaf(cx,w.x,ax_[4*kk+0]); ay_[4*kk+0]=fmaf(cy,w.x,ay_[4*kk+0]); az_[4*kk+0]=fmaf(cz,w.x,az_[4*kk+0]);
        ax_[4*kk+1]=fmaf(cx,w.y,ax_[4*kk+1]); ay_[4*kk+1]=fmaf(cy,w.y,ay_[4*kk+1]); az_[4*kk+1]=fmaf(cz,w.y,az_[4*kk+1]);
        ax_[4*kk+2]=fmaf(cx,w.z,ax_[4*kk+2]); ay_[4*kk+2]=fmaf(cy,w.z,ay_[4*kk+2]); az_[4*kk+2]=fmaf(cz,w.z,az_[4*kk+2]);
        ax_[4*kk+3]=fmaf(cx,w.w,ax_[4*kk+3]); ay_[4*kk+3]=fmaf(cy,w.w,ay_[4*kk+3]); az_[4*kk+3]=fmaf(cz,w.w,az_[4*kk+3]);
    }
}

// split fp32 -> fp16 hi + fp16 residual (exact to ~2^-22 combined)
__device__ __forceinline__ void split8(const float* p, half8& ah, half8& al) {
#pragma unroll
    for (int j = 0; j < 8; ++j) {
        _Float16 h = (_Float16)p[j];
        ah[j] = h;
        al[j] = (_Float16)(p[j] - (float)h);
    }
}
__device__ __forceinline__ floatx4 mfma3(half8 ah, half8 al, half8 bh, half8 bl, floatx4 acc) {
    acc = __builtin_amdgcn_mfma_f32_16x16x32_f16(ah, bh, acc, 0, 0, 0);
    acc = __builtin_amdgcn_mfma_f32_16x16x32_f16(al, bh, acc, 0, 0, 0);
    acc = __builtin_amdgcn_mfma_f32_16x16x32_f16(ah, bl, acc, 0, 0, 0);
    return acc;
}

// =====================================================================
// Weight prep: fp32 -> (fp16 hi, fp16 lo) B-fragments, norms folded.
// B[(t_n*Tk + t_k)*64 + lane][8]: lane=(q,n) holds B[k=32*t_k+8q+j][col=16*t_n+n]
// =====================================================================
__global__ void prep_w(const float* __restrict__ W1ss, const float* __restrict__ W1sv,
                       const float* __restrict__ W1vs, const float* __restrict__ W1vvs,
                       const float* __restrict__ W1vvv,
                       const float* __restrict__ W2ss, const float* __restrict__ W2sv,
                       const float* __restrict__ W2vs, const float* __restrict__ W2vvs,
                       const float* __restrict__ W2vvv,
                       _Float16* B1sh, _Float16* B1sl, _Float16* B1vh, _Float16* B1vl,
                       _Float16* B2sh, _Float16* B2sl, _Float16* B2vh, _Float16* B2vl)
{
    const int tid = threadIdx.x;
    // B1s: Tk=10, K=320 (256 ss + 64 vvs), 16 cols
    for (int idx = tid; idx < 10*512; idx += 256) {
        int t_k = idx >> 9, lane = (idx >> 3) & 63, j = idx & 7;
        int q = lane >> 4, n = lane & 15;
        int k = t_k*32 + q*8 + j;
        float v;
        if (k < 256) { int i = k>>4, jj = k&15; v = W1ss[(i*16+jj)*16+n] * C_SS16; }
        else { int kk = k-256; int i = kk>>3, jj = kk&7; v = W1vvs[(i*8+jj)*16+n] * C_UNI; }
        _Float16 h = (_Float16)v;
        B1sh[idx] = h; B1sl[idx] = (_Float16)(v - (float)h);
    }
    // B1v: Tk=10, K=320 (128 sv + 128 vs + 64 vvv), 8 cols (8..15 zero)
    for (int idx = tid; idx < 10*512; idx += 256) {
        int t_k = idx >> 9, lane = (idx >> 3) & 63, j = idx & 7;
        int q = lane >> 4, n = lane & 15;
        int k = t_k*32 + q*8 + j;
        float v = 0.f;
        if (n < 8) {
            if (k < 128) { int i = k>>3, jj = k&7; v = W1sv[(i*8+jj)*8+n] * C_UNI; }
            else if (k < 256) { int kk = k-128; int i = kk>>4, jj = kk&15; v = W1vs[(i*16+jj)*8+n] * C_UNI; }
            else { int kk = k-256; int i = kk>>3, jj = kk&7; v = W1vvv[(i*8+jj)*8+n] * C_UNI; }
        }
        _Float16 h = (_Float16)v;
        B1vh[idx] = h; B1vl[idx] = (_Float16)(v - (float)h);
    }
    // B2s: Tn=3, Tk=6, K=192 (128 ss + 64 vvs), 48 cols
    for (int idx = tid; idx < 3*6*512; idx += 256) {
        int tn = idx / 3072, t_k = (idx % 3072) >> 9, lane = (idx >> 3) & 63, j = idx & 7;
        int q = lane >> 4, n = lane & 15, col = tn*16 + n;
        int k = t_k*32 + q*8 + j;
        float v;
        if (k < 128) { int i = k>>3, jj = k&7; v = W2ss[(i*8+jj)*48+col] * C2_SS; }
        else { int kk = k-128; int i = kk>>3, jj = kk&7; v = W2vvs[(i*8+jj)*48+col] * C_UNI; }
        _Float16 h = (_Float16)v;
        B2sh[idx] = h; B2sl[idx] = (_Float16)(v - (float)h);
    }
    // B2v: Tk=8, K=256 (128 sv + 64 vs + 64 vvv), 16 cols
    for (int idx = tid; idx < 8*512; idx += 256) {
        int t_k = idx >> 9, lane = (idx >> 3) & 63, j = idx & 7;
        int q = lane >> 4, n = lane & 15;
        int k = t_k*32 + q*8 + j;
        float v;
        if (k < 128) { int i = k>>3, jj = k&7; v = W2sv[(i*8+jj)*16+n] * C_UNI; }
        else if (k < 192) { int kk = k-128; int i = kk>>3, jj = kk&7; v = W2vs[(i*8+jj)*16+n] * C2_VS; }
        else { int kk = k-192; int i = kk>>3, jj = kk&7; v = W2vvv[(i*8+jj)*16+n] * C_UNI; }
        _Float16 h = (_Float16)v;
        B2vh[idx] = h; B2vl[idx] = (_Float16)(v - (float)h);
    }
}

// =====================================================================
// Fused edge kernel: stage1 MFMA -> LDS transpose -> stage2 MFMA -> gate
// -> linear -> m2h[E][40] fp32 messages. Wave = 16 edges; LDS wave-private.
// =====================================================================
__global__ __launch_bounds__(256)
void edge_fused(const float* __restrict__ ns, const float* __restrict__ nv,
                const float* __restrict__ edge_s, const float* __restrict__ edge_v,
                const int* __restrict__ ei,
                const _Float16* __restrict__ B1sh, const _Float16* __restrict__ B1sl,
                const _Float16* __restrict__ B1vh, const _Float16* __restrict__ B1vl,
                const _Float16* __restrict__ B2sh, const _Float16* __restrict__ B2sl,
                const _Float16* __restrict__ B2vh, const _Float16* __restrict__ B2vl,
                const float* __restrict__ Lms, const float* __restrict__ Lmv,
                float* __restrict__ m2h, int E)
{
    __shared__ float mT[4][16*41];       // [wave][edge][41] m transpose
    __shared__ float ep[4][2][16*49];    // [wave][{hs,gv}][edge][49]
    const int lane = threadIdx.x & 63;
    const int wv = threadIdx.x >> 6;
    const int e0 = (blockIdx.x*4 + wv) * 16;
    const int q = lane >> 4, n = lane & 15;
    const int e = min(e0 + n, E - 1);
    const int qh = q >> 1, ql = q & 1;
    const int r = ei[e], c2 = ei[E + e];

    // ---------------- stage 1 feature slices ----------------
    float rs_sel[8], rs4[4], rva[2][3], rvs[4][3], csh[8], cv[8][3];
#pragma unroll
    for (int t = 0; t < 8; ++t) rs_sel[t] = ns[(size_t)r*16 + 2*t + qh];
#pragma unroll
    for (int t = 0; t < 4; ++t) rs4[t] = ns[(size_t)r*16 + 4*t + q];
#pragma unroll
    for (int cc = 0; cc < 3; ++cc) {
        rva[0][cc] = nv[(size_t)r*24 + 3*q + cc];
        rva[1][cc] = nv[(size_t)r*24 + 3*(q+4) + cc];
    }
#pragma unroll
    for (int u = 0; u < 4; ++u)
#pragma unroll
        for (int cc = 0; cc < 3; ++cc) rvs[u][cc] = nv[(size_t)r*24 + 3*(2*u+qh) + cc];
    {
        const float4* p = (const float4*)(ns + (size_t)c2*16 + ql*8);
#pragma unroll
        for (int t = 0; t < 2; ++t) { float4 v = p[t]; csh[4*t]=v.x; csh[4*t+1]=v.y; csh[4*t+2]=v.z; csh[4*t+3]=v.w; }
        const float4* pv = (const float4*)(nv + (size_t)c2*24);
        float tmp[24];
#pragma unroll
        for (int t = 0; t < 6; ++t) { float4 v = pv[t]; tmp[4*t]=v.x; tmp[4*t+1]=v.y; tmp[4*t+2]=v.z; tmp[4*t+3]=v.w; }
#pragma unroll
        for (int k = 0; k < 8; ++k) { cv[k][0]=tmp[3*k]; cv[k][1]=tmp[3*k+1]; cv[k][2]=tmp[3*k+2]; }
    }

    const half8* B1sH = (const half8*)B1sh; const half8* B1sL = (const half8*)B1sl;
    const half8* B1vH = (const half8*)B1vh; const half8* B1vL = (const half8*)B1vl;

    // ---- stage1 scalar GEMM: [16e x 320] @ [320 x 16] ----
    {
        floatx4 acc = {0.f, 0.f, 0.f, 0.f};
#pragma unroll
        for (int t = 0; t < 10; ++t) {
            float p[8];
            if (t < 8) {
                const float m = rs_sel[t];
#pragma unroll
                for (int j = 0; j < 8; ++j) p[j] = m * csh[j];
            } else {
                const int u = t - 8;
                const float vx = rva[u][0], vy = rva[u][1], vz = rva[u][2];
#pragma unroll
                for (int j = 0; j < 8; ++j) p[j] = fmaf(vx, cv[j][0], fmaf(vy, cv[j][1], vz*cv[j][2]));
            }
            half8 ah, al; split8(p, ah, al);
            acc = mfma3(ah, al, B1sH[t*64 + lane], B1sL[t*64 + lane], acc);
        }
#pragma unroll
        for (int r2 = 0; r2 < 4; ++r2)
            mT[wv][(q*4 + r2)*41 + n] = acc[r2];
    }
    // ---- stage1 vector GEMMs per component: [16e x 320] @ [320 x 8] ----
#pragma unroll 1
    for (int c = 0; c < 3; ++c) {
        const int c1 = (c+1)%3, c2i = (c+2)%3;
        floatx4 acc = {0.f, 0.f, 0.f, 0.f};
#pragma unroll
        for (int t = 0; t < 10; ++t) {
            float p[8];
            if (t < 4) {
                const float m = rs4[t];
#pragma unroll
                for (int j = 0; j < 8; ++j) p[j] = m * cv[j][c];
            } else if (t < 8) {
                const float m = rvs[t-4][c];
#pragma unroll
                for (int j = 0; j < 8; ++j) p[j] = m * csh[j];
            } else {
                const int u = t - 8;
                const float v1 = rva[u][c1], v2 = rva[u][c2i];
#pragma unroll
                for (int j = 0; j < 8; ++j) p[j] = v1*cv[j][c2i] - v2*cv[j][c1];
            }
            half8 ah, al; split8(p, ah, al);
            acc = mfma3(ah, al, B1vH[t*64 + lane], B1vL[t*64 + lane], acc);
        }
        if (n < 8) {
#pragma unroll
            for (int r2 = 0; r2 < 4; ++r2)
                mT[wv][(q*4 + r2)*41 + 16 + 3*n + c] = acc[r2];
        }
    }
    __syncthreads();

    // ---------------- stage 2 inputs ----------------
    float msr[4], mva[2][3], es[8], ev[8][3];
#pragma unroll
    for (int t = 0; t < 4; ++t) msr[t] = mT[wv][n*41 + 4*t + q];
#pragma unroll
    for (int u = 0; u < 2; ++u)
#pragma unroll
        for (int cc = 0; cc < 3; ++cc) mva[u][cc] = mT[wv][n*41 + 16 + 3*(4*u+q) + cc];
    {
        const float4* p = (const float4*)(edge_s + (size_t)e*8);
#pragma unroll
        for (int t = 0; t < 2; ++t) { float4 v = p[t]; es[4*t]=v.x; es[4*t+1]=v.y; es[4*t+2]=v.z; es[4*t+3]=v.w; }
        const float4* pv = (const float4*)(edge_v + (size_t)e*24);
        float tmp[24];
#pragma unroll
        for (int t = 0; t < 6; ++t) { float4 v = pv[t]; tmp[4*t]=v.x; tmp[4*t+1]=v.y; tmp[4*t+2]=v.z; tmp[4*t+3]=v.w; }
#pragma unroll
        for (int k = 0; k < 8; ++k) { ev[k][0]=tmp[3*k]; ev[k][1]=tmp[3*k+1]; ev[k][2]=tmp[3*k+2]; }
    }

    const half8* B2sH = (const half8*)B2sh; const half8* B2sL = (const half8*)B2sl;
    const half8* B2vH = (const half8*)B2vh; const half8* B2vL = (const half8*)B2vl;

    // ---- stage2 scalar GEMM: [16e x 192] @ [192 x 48] ----
    floatx4 accs[3];
#pragma unroll
    for (int t = 0; t < 3; ++t) accs[t] = (floatx4){0.f,0.f,0.f,0.f};
#pragma unroll
    for (int t = 0; t < 6; ++t) {
        float p[8];
        if (t < 4) {
            const float m = msr[t];
#pragma unroll
            for (int j = 0; j < 8; ++j) p[j] = m * es[j];
        } else {
            const int u = t - 4;
            const float vx = mva[u][0], vy = mva[u][1], vz = mva[u][2];
#pragma unroll
            for (int j = 0; j < 8; ++j) p[j] = fmaf(vx, ev[j][0], fmaf(vy, ev[j][1], vz*ev[j][2]));
        }
        half8 ah, al; split8(p, ah, al);
#pragma unroll
        for (int tn = 0; tn < 3; ++tn)
            accs[tn] = mfma3(ah, al, B2sH[(tn*6 + t)*64 + lane], B2sL[(tn*6 + t)*64 + lane], accs[tn]);
    }

    // stage hs: cols<32 silu*C_LS, cols 32..47 raw gates
    float* hsL = &ep[wv][0][0];
    float* gvL = &ep[wv][1][0];
#pragma unroll
    for (int t = 0; t < 3; ++t)
#pragma unroll
        for (int r2 = 0; r2 < 4; ++r2) {
            const int row = q*4 + r2;
            const float v = accs[t][r2];
            if (t < 2) hsL[row*49 + t*16 + n] = v / (1.f + __expf(-v)) * C_LS;
            else       hsL[row*49 + 32 + n] = v;
        }
    __syncthreads();

    // scalar epilogue: edge m_e=n, out cols 4q..4q+3 (fp32 messages)
    {
        float os[4] = {0.f, 0.f, 0.f, 0.f};
#pragma unroll 4
        for (int s = 0; s < 32; ++s) {
            const float hv_ = hsL[n*49 + s];
            const float4 w = *(const float4*)(Lms + s*16 + 4*q);
            os[0] = fmaf(hv_, w.x, os[0]); os[1] = fmaf(hv_, w.y, os[1]);
            os[2] = fmaf(hv_, w.z, os[2]); os[3] = fmaf(hv_, w.w, os[3]);
        }
        if (e0 + n < E) {
#pragma unroll
            for (int u = 0; u < 4; ++u)
                m2h[(size_t)(e0 + n)*40 + 4*q + u] = os[u];
        }
    }

    // ---- stage2 vector GEMMs: [16e x 256] @ [256 x 16] ----
    floatx4 accv[3];
#pragma unroll 1
    for (int c = 0; c < 3; ++c) {
        const int c1 = (c+1)%3, c2i = (c+2)%3;
        floatx4 acc = {0.f, 0.f, 0.f, 0.f};
#pragma unroll
        for (int t = 0; t < 8; ++t) {
            float p[8];
            if (t < 4) {
                const float m = msr[t];
#pragma unroll
                for (int j = 0; j < 8; ++j) p[j] = m * ev[j][c];
            } else if (t < 6) {
                const float m = mva[t-4][c];
#pragma unroll
                for (int j = 0; j < 8; ++j) p[j] = m * es[j];
            } else {
                const int u = t - 6;
                const float v1 = mva[u][c1], v2 = mva[u][c2i];
#pragma unroll
                for (int j = 0; j < 8; ++j) p[j] = v1*ev[j][c2i] - v2*ev[j][c1];
            }
            half8 ah, al; split8(p, ah, al);
            acc = mfma3(ah, al, B2vH[t*64 + lane], B2vL[t*64 + lane], acc);
        }
        accv[c] = acc;
    }
    // gate (channel = col n; gate value written by this same lane)
#pragma unroll
    for (int r2 = 0; r2 < 4; ++r2) {
        const int row = q*4 + r2;
        const float gt = C_LV / (1.f + __expf(-hsL[row*49 + 32 + n]));
#pragma unroll
        for (int c = 0; c < 3; ++c) gvL[row*49 + c*16 + n] = accv[c][r2] * gt;
    }
    __syncthreads();

    // vector epilogue: edge m_e=n, out channels {2q, 2q+1} (fp32 messages)
    {
        float ov[3][2] = {{0.f,0.f},{0.f,0.f},{0.f,0.f}};
#pragma unroll 4
        for (int k = 0; k < 16; ++k) {
            const float2 w = *(const float2*)(Lmv + k*8 + 2*q);
#pragma unroll
            for (int c = 0; c < 3; ++c) {
                const float gv = gvL[n*49 + c*16 + k];
                ov[c][0] = fmaf(gv, w.x, ov[c][0]);
                ov[c][1] = fmaf(gv, w.y, ov[c][1]);
            }
        }
        if (e0 + n < E) {
#pragma unroll
            for (int o2 = 0; o2 < 2; ++o2)
#pragma unroll
                for (int c = 0; c < 3; ++c)
                    m2h[(size_t)(e0 + n)*40 + 16 + 3*(2*q + o2) + c] = ov[c][o2];
        }
    }
}

// =====================================================================
// CSR build
// =====================================================================
__global__ void hist_k(const int* __restrict__ ei, int* __restrict__ deg, int E) {
    const int e = blockIdx.x*256 + threadIdx.x;
    if (e < E) atomicAdd(&deg[ei[E + e]], 1);
}
__global__ void scan_k(const int* __restrict__ deg, int* __restrict__ offs,
                       int* __restrict__ pos, int N) {
    __shared__ int sm[1024];
    const int t = threadIdx.x;
    const int chunk = (N + 1023) / 1024;
    const int lo = t * chunk, hi = min(lo + chunk, N);
    int s = 0;
    for (int i = lo; i < hi; ++i) s += deg[i];
    sm[t] = s; __syncthreads();
    for (int off = 1; off < 1024; off <<= 1) {
        int v = (t >= off) ? sm[t - off] : 0;
        __syncthreads();
        sm[t] += v;
        __syncthreads();
    }
    int base = sm[t] - s;
    for (int i = lo; i < hi; ++i) { offs[i] = base; pos[i] = base; base += deg[i]; }
}
__global__ void fill_k(const int* __restrict__ ei, int* __restrict__ pos,
                       int* __restrict__ order, int E) {
    const int e = blockIdx.x*256 + threadIdx.x;
    if (e < E) { int p = atomicAdd(&pos[ei[E + e]], 1); order[p] = e; }
}

// =====================================================================
// node_upd: CSR gather-aggregate (fp32 messages) + update TP -> out[N,40]
// =====================================================================
__global__ __launch_bounds__(256)
void node_upd(const float* __restrict__ node_s, const float* __restrict__ node_v,
              const float* __restrict__ m2h,
              const int* __restrict__ deg, const int* __restrict__ offs,
              const int* __restrict__ order,
              const float* __restrict__ gW3ss, const float* __restrict__ gW3sv,
              const float* __restrict__ gW3vs, const float* __restrict__ gW3vvs,
              const float* __restrict__ gW3vvv,
              const float* __restrict__ gLus, const float* __restrict__ gLuv,
              float* __restrict__ out, int N)
{
    extern __shared__ float lds[];   // [40][256]
    const int tid = threadIdx.x;
    const int n = blockIdx.x*256 + tid;
    if (n >= N) return;
#define Lrs(i)  lds[(i)*256 + tid]
#define Lrvx(i) lds[(16+(i))*256 + tid]
#define Lrvy(i) lds[(24+(i))*256 + tid]
#define Lrvz(i) lds[(32+(i))*256 + tid]
    {
        const float4* p = (const float4*)(node_s + (size_t)n*16);
#pragma unroll
        for (int q=0;q<4;++q){ float4 t=p[q]; Lrs(4*q)=t.x; Lrs(4*q+1)=t.y; Lrs(4*q+2)=t.z; Lrs(4*q+3)=t.w; }
        const float4* pv = (const float4*)(node_v + (size_t)n*24);
        float tmp[24];
#pragma unroll
        for (int q=0;q<6;++q){ float4 t=pv[q]; tmp[4*q]=t.x; tmp[4*q+1]=t.y; tmp[4*q+2]=t.z; tmp[4*q+3]=t.w; }
#pragma unroll
        for (int k=0;k<8;++k){ Lrvx(k)=tmp[3*k]; Lrvy(k)=tmp[3*k+1]; Lrvz(k)=tmp[3*k+2]; }
    }
    float as_[16], avx[8], avy[8], avz[8];
#pragma unroll
    for (int j=0;j<16;++j) as_[j]=0.f;
#pragma unroll
    for (int j=0;j<8;++j){ avx[j]=0.f; avy[j]=0.f; avz[j]=0.f; }
    {
        const int cnt = deg[n], base = offs[n];
        for (int t = 0; t < cnt; ++t) {
            const int id = order[base + t];
            const float4* mp = (const float4*)(m2h + (size_t)id*40);
            float tmp[40];
#pragma unroll
            for (int u=0;u<10;++u){ float4 v=mp[u]; tmp[4*u]=v.x; tmp[4*u+1]=v.y; tmp[4*u+2]=v.z; tmp[4*u+3]=v.w; }
#pragma unroll
            for (int u=0;u<16;++u) as_[u] += tmp[u];
#pragma unroll
            for (int k=0;k<8;++k){ avx[k]+=tmp[16+3*k]; avy[k]+=tmp[16+3*k+1]; avz[k]+=tmp[16+3*k+2]; }
        }
    }

    // Phase A: hs[48]
    float g[16];
    {
        float hs[48];
#pragma unroll
        for (int k=0;k<48;++k) hs[k]=0.f;
#pragma unroll 1
        for (int i=0;i<16;++i) {
            const float a = Lrs(i)*C_SS16;
#pragma unroll
            for (int j=0;j<16;++j)
                fma48(hs, a*as_[j], (const float4*)&gW3ss[(i*16+j)*48]);
        }
#pragma unroll 1
        for (int i=0;i<8;++i) {
            const float ax=Lrvx(i), ay=Lrvy(i), az=Lrvz(i);
#pragma unroll
            for (int j=0;j<8;++j) {
                const float d = fmaf(ax,avx[j],fmaf(ay,avy[j],az*avz[j]))*C_UNI;
                fma48(hs, d, (const float4*)&gW3vvs[(i*8+j)*48]);
            }
        }
        float os[16];
#pragma unroll
        for (int k=0;k<16;++k) os[k]=0.f;
#pragma unroll
        for (int i=0;i<32;++i) {
            const float x = hs[i];
            const float a = x/(1.f+__expf(-x))*C_LS;
            fma16(os, a, (const float4*)&gLus[i*16]);
        }
        float4* o4 = (float4*)(out + (size_t)n*40);
#pragma unroll
        for (int q=0;q<4;++q) o4[q] = make_float4(os[4*q],os[4*q+1],os[4*q+2],os[4*q+3]);
#pragma unroll
        for (int i=0;i<16;++i) g[i] = C_LV/(1.f+__expf(-hs[32+i]));
    }

    // Phase B: hv[16][3]
    float hvx[16],hvy[16],hvz[16];
#pragma unroll
    for (int k=0;k<16;++k){ hvx[k]=0.f; hvy[k]=0.f; hvz[k]=0.f; }
#pragma unroll
    for (int j=0;j<8;++j) {
        float t[16];
#pragma unroll
        for (int k=0;k<16;++k) t[k]=0.f;
#pragma unroll 1
        for (int i=0;i<16;++i)
            fma16(t, Lrs(i), (const float4*)&gW3sv[(i*8+j)*16]);
        const float bx=avx[j]*C_UNI, by=avy[j]*C_UNI, bz=avz[j]*C_UNI;
#pragma unroll
        for (int k=0;k<16;++k){ hvx[k]=fmaf(t[k],bx,hvx[k]); hvy[k]=fmaf(t[k],by,hvy[k]); hvz[k]=fmaf(t[k],bz,hvz[k]); }
    }
#pragma unroll 1
    for (int i=0;i<8;++i) {
        float t[16];
#pragma unroll
        for (int k=0;k<16;++k) t[k]=0.f;
#pragma unroll
        for (int j=0;j<16;++j)
            fma16(t, as_[j], (const float4*)&gW3vs[(i*16+j)*16]);
        const float ax=Lrvx(i)*C_UNI, ay=Lrvy(i)*C_UNI, az=Lrvz(i)*C_UNI;
#pragma unroll
        for (int k=0;k<16;++k){ hvx[k]=fmaf(t[k],ax,hvx[k]); hvy[k]=fmaf(t[k],ay,hvy[k]); hvz[k]=fmaf(t[k],az,hvz[k]); }
    }
#pragma unroll 1
    for (int i=0;i<8;++i) {
        const float ax=Lrvx(i), ay=Lrvy(i), az=Lrvz(i);
#pragma unroll
        for (int j=0;j<8;++j) {
            const float bx=avx[j], by=avy[j], bz=avz[j];
            const float cx=(ay*bz-az*by)*C_UNI, cy=(az*bx-ax*bz)*C_UNI, cz=(ax*by-ay*bx)*C_UNI;
            vfma16(hvx,hvy,hvz, cx,cy,cz, (const float4*)&gW3vvv[(i*8+j)*16]);
        }
    }
#undef Lrs
#undef Lrvx
#undef Lrvy
#undef Lrvz
    float ovx[8],ovy[8],ovz[8];
#pragma unroll
    for (int k=0;k<8;++k){ ovx[k]=0.f; ovy[k]=0.f; ovz[k]=0.f; }
#pragma unroll
    for (int i=0;i<16;++i)
        vfma8(ovx,ovy,ovz, hvx[i]*g[i], hvy[i]*g[i], hvz[i]*g[i], (const float4*)&gLuv[i*8]);
    float ob[24];
#pragma unroll
    for (int k=0;k<8;++k){ ob[3*k]=ovx[k]; ob[3*k+1]=ovy[k]; ob[3*k+2]=ovz[k]; }
    float4* o4 = (float4*)(out + (size_t)n*40 + 16);
#pragma unroll
    for (int q=0;q<6;++q) o4[q]=make_float4(ob[4*q],ob[4*q+1],ob[4*q+2],ob[4*q+3]);
}

// =====================================================================
extern "C" void kernel_launch(void* const* d_in, const int* in_sizes, int n_in,
                              void* d_out, int out_size, void* d_ws, size_t ws_size,
                              hipStream_t stream) {
    const float* node_s = (const float*)d_in[0];
    const float* node_v = (const float*)d_in[1];
    const float* edge_s = (const float*)d_in[3];
    const float* edge_v = (const float*)d_in[4];
    const int*   ei     = (const int*)d_in[5];
    const float* W1ss = (const float*)d_in[6];
    const float* W1sv = (const float*)d_in[7];
    const float* W1vs = (const float*)d_in[8];
    const float* W1vvs= (const float*)d_in[9];
    const float* W1vvv= (const float*)d_in[10];
    const float* W2ss = (const float*)d_in[11];
    const float* W2sv = (const float*)d_in[12];
    const float* W2vs = (const float*)d_in[13];
    const float* W2vvs= (const float*)d_in[14];
    const float* W2vvv= (const float*)d_in[15];
    const float* Lms  = (const float*)d_in[16];
    const float* Lmv  = (const float*)d_in[17];
    const float* W3ss = (const float*)d_in[18];
    const float* W3sv = (const float*)d_in[19];
    const float* W3vs = (const float*)d_in[20];
    const float* W3vvs= (const float*)d_in[21];
    const float* W3vvv= (const float*)d_in[22];
    const float* Lus  = (const float*)d_in[23];
    const float* Luv  = (const float*)d_in[24];

    float* out = (float*)d_out;
    const int N = in_sizes[0] / 16;
    const int E = in_sizes[5] / 2;

    // ws layout: fp16 B-frags, then fp32 messages (16B-aligned), then CSR ints
    _Float16* B1sh = (_Float16*)d_ws;             // 5120
    _Float16* B1sl = B1sh + 5120;
    _Float16* B1vh = B1sl + 5120;
    _Float16* B1vl = B1vh + 5120;
    _Float16* B2sh = B1vl + 5120;                 // 9216
    _Float16* B2sl = B2sh + 9216;
    _Float16* B2vh = B2sl + 9216;                 // 4096
    _Float16* B2vl = B2vh + 4096;                 // ends at 47104 halves = 94208 B
    float* m2h = (float*)((char*)d_ws + 94208);   // [E][40] fp32 (16B-aligned)
    int* deg   = (int*)(m2h + (size_t)40*E);      // N
    int* offs  = deg + N;
    int* pos   = offs + N;
    int* order = pos + N;                         // E

    hipMemsetAsync(deg, 0, (size_t)N * sizeof(int), stream);

    prep_w<<<1, 256, 0, stream>>>(W1ss, W1sv, W1vs, W1vvs, W1vvv,
                                  W2ss, W2sv, W2vs, W2vvs, W2vvv,
                                  B1sh, B1sl, B1vh, B1vl, B2sh, B2sl, B2vh, B2vl);

    hist_k<<<(E + 255)/256, 256, 0, stream>>>(ei, deg, E);
    scan_k<<<1, 1024, 0, stream>>>(deg, offs, pos, N);
    fill_k<<<(E + 255)/256, 256, 0, stream>>>(ei, pos, order, E);

    const int tpblocks = (E + 63) / 64;   // 4 waves/block, 16 edges/wave
    edge_fused<<<tpblocks, 256, 0, stream>>>(
        node_s, node_v, edge_s, edge_v, ei,
        B1sh, B1sl, B1vh, B1vl, B2sh, B2sl, B2vh, B2vl,
        Lms, Lmv, m2h, E);

    node_upd<<<(N + 255)/256, 256, 40*256*sizeof(float), stream>>>(
        node_s, node_v, m2h, deg, offs, order,
        W3ss, W3sv, W3vs, W3vvs, W3vvv, Lus, Luv, out, N);
}

// Round 7
// 686.769 us; speedup vs baseline: 3.8149x; 1.1737x over previous
//
#include <hip/hip_runtime.h>
#include <math.h>

typedef _Float16 half8 __attribute__((ext_vector_type(8)));
typedef float floatx4 __attribute__((ext_vector_type(4)));

constexpr float C_SS16 = 0.04419417382415922f;  // i2/16
constexpr float C_UNI  = 0.05103103630798288f;  // i3/sqrt(128)
constexpr float C2_SS  = 0.0625f;               // i2/sqrt(128)
constexpr float C2_VS  = 0.07216878364870323f;  // i3/8
constexpr float C_LS   = 0.17677669529663687f;  // 1/sqrt(32)
constexpr float C_LV   = 0.25f;                 // 1/sqrt(16)
constexpr float RS     = 2048.0f;               // residual scale (keeps lo-parts normal in fp16)
constexpr float RSI    = 1.0f / 2048.0f;

// split fp32 -> fp16 hi + SCALED fp16 residual (residual*2048 stays normal-range)
__device__ __forceinline__ void split8s(const float* p, half8& ah, half8& alS) {
#pragma unroll
    for (int j = 0; j < 8; ++j) {
        _Float16 h = (_Float16)p[j];
        ah[j] = h;
        alS[j] = (_Float16)((p[j] - (float)h) * RS);
    }
}
// 3-term split MFMA with separate scaled-residual accumulator
__device__ __forceinline__ void mfma_tri(half8 ah, half8 alS, half8 bh, half8 blS,
                                         floatx4& acc, floatx4& accR) {
    acc  = __builtin_amdgcn_mfma_f32_16x16x32_f16(ah,  bh,  acc,  0, 0, 0);
    accR = __builtin_amdgcn_mfma_f32_16x16x32_f16(alS, bh,  accR, 0, 0, 0);
    accR = __builtin_amdgcn_mfma_f32_16x16x32_f16(ah,  blS, accR, 0, 0, 0);
}

// =====================================================================
// Weight prep: fp32 -> (fp16 hi, fp16 lo*2048) B-fragments, norms folded.
// B[(t_n*Tk + t_k)*64 + lane][8]: lane=(q,n) holds B[k=32*t_k+8q+j][col=16*t_n+n]
// =====================================================================
__global__ void prep_w(const float* __restrict__ W1ss, const float* __restrict__ W1sv,
                       const float* __restrict__ W1vs, const float* __restrict__ W1vvs,
                       const float* __restrict__ W1vvv,
                       const float* __restrict__ W2ss, const float* __restrict__ W2sv,
                       const float* __restrict__ W2vs, const float* __restrict__ W2vvs,
                       const float* __restrict__ W2vvv,
                       const float* __restrict__ W3ss, const float* __restrict__ W3sv,
                       const float* __restrict__ W3vs, const float* __restrict__ W3vvs,
                       const float* __restrict__ W3vvv,
                       _Float16* B1sh, _Float16* B1sl, _Float16* B1vh, _Float16* B1vl,
                       _Float16* B2sh, _Float16* B2sl, _Float16* B2vh, _Float16* B2vl,
                       _Float16* B3sh, _Float16* B3sl, _Float16* B3vh, _Float16* B3vl)
{
    const int tid = threadIdx.x;
    // B1s: Tk=10, K=320 (256 ss + 64 vvs), 16 cols
    for (int idx = tid; idx < 10*512; idx += 256) {
        int t_k = idx >> 9, lane = (idx >> 3) & 63, j = idx & 7;
        int q = lane >> 4, n = lane & 15;
        int k = t_k*32 + q*8 + j;
        float v;
        if (k < 256) { int i = k>>4, jj = k&15; v = W1ss[(i*16+jj)*16+n] * C_SS16; }
        else { int kk = k-256; int i = kk>>3, jj = kk&7; v = W1vvs[(i*8+jj)*16+n] * C_UNI; }
        _Float16 h = (_Float16)v;
        B1sh[idx] = h; B1sl[idx] = (_Float16)((v - (float)h) * RS);
    }
    // B1v: Tk=10, K=320 (128 sv + 128 vs + 64 vvv), 8 cols (8..15 zero)
    for (int idx = tid; idx < 10*512; idx += 256) {
        int t_k = idx >> 9, lane = (idx >> 3) & 63, j = idx & 7;
        int q = lane >> 4, n = lane & 15;
        int k = t_k*32 + q*8 + j;
        float v = 0.f;
        if (n < 8) {
            if (k < 128) { int i = k>>3, jj = k&7; v = W1sv[(i*8+jj)*8+n] * C_UNI; }
            else if (k < 256) { int kk = k-128; int i = kk>>4, jj = kk&15; v = W1vs[(i*16+jj)*8+n] * C_UNI; }
            else { int kk = k-256; int i = kk>>3, jj = kk&7; v = W1vvv[(i*8+jj)*8+n] * C_UNI; }
        }
        _Float16 h = (_Float16)v;
        B1vh[idx] = h; B1vl[idx] = (_Float16)((v - (float)h) * RS);
    }
    // B2s: Tn=3, Tk=6, K=192 (128 ss + 64 vvs), 48 cols
    for (int idx = tid; idx < 3*6*512; idx += 256) {
        int tn = idx / 3072, t_k = (idx % 3072) >> 9, lane = (idx >> 3) & 63, j = idx & 7;
        int q = lane >> 4, n = lane & 15, col = tn*16 + n;
        int k = t_k*32 + q*8 + j;
        float v;
        if (k < 128) { int i = k>>3, jj = k&7; v = W2ss[(i*8+jj)*48+col] * C2_SS; }
        else { int kk = k-128; int i = kk>>3, jj = kk&7; v = W2vvs[(i*8+jj)*48+col] * C_UNI; }
        _Float16 h = (_Float16)v;
        B2sh[idx] = h; B2sl[idx] = (_Float16)((v - (float)h) * RS);
    }
    // B2v: Tk=8, K=256 (128 sv + 64 vs + 64 vvv), 16 cols
    for (int idx = tid; idx < 8*512; idx += 256) {
        int t_k = idx >> 9, lane = (idx >> 3) & 63, j = idx & 7;
        int q = lane >> 4, n = lane & 15;
        int k = t_k*32 + q*8 + j;
        float v;
        if (k < 128) { int i = k>>3, jj = k&7; v = W2sv[(i*8+jj)*16+n] * C_UNI; }
        else if (k < 192) { int kk = k-128; int i = kk>>3, jj = kk&7; v = W2vs[(i*8+jj)*16+n] * C2_VS; }
        else { int kk = k-192; int i = kk>>3, jj = kk&7; v = W2vvv[(i*8+jj)*16+n] * C_UNI; }
        _Float16 h = (_Float16)v;
        B2vh[idx] = h; B2vl[idx] = (_Float16)((v - (float)h) * RS);
    }
    // B3s: Tn=3, Tk=10, K=320 (256 ss + 64 vvs), 48 cols
    for (int idx = tid; idx < 3*10*512; idx += 256) {
        int tn = idx / 5120, rem = idx % 5120;
        int t_k = rem >> 9, lane = (rem >> 3) & 63, j = rem & 7;
        int q = lane >> 4, n = lane & 15, col = tn*16 + n;
        int k = t_k*32 + q*8 + j;
        float v;
        if (k < 256) { int i = k>>4, jj = k&15; v = W3ss[(i*16+jj)*48+col] * C_SS16; }
        else { int kk = k-256; int i = kk>>3, jj = kk&7; v = W3vvs[(i*8+jj)*48+col] * C_UNI; }
        _Float16 h = (_Float16)v;
        B3sh[idx] = h; B3sl[idx] = (_Float16)((v - (float)h) * RS);
    }
    // B3v: Tk=10, K=320 (128 sv + 128 vs + 64 vvv), 16 cols
    for (int idx = tid; idx < 10*512; idx += 256) {
        int t_k = idx >> 9, lane = (idx >> 3) & 63, j = idx & 7;
        int q = lane >> 4, n = lane & 15;
        int k = t_k*32 + q*8 + j;
        float v;
        if (k < 128) { int i = k>>3, jj = k&7; v = W3sv[(i*8+jj)*16+n] * C_UNI; }
        else if (k < 256) { int kk = k-128; int i = kk>>4, jj = kk&15; v = W3vs[(i*16+jj)*16+n] * C_UNI; }
        else { int kk = k-256; int i = kk>>3, jj = kk&7; v = W3vvv[(i*8+jj)*16+n] * C_UNI; }
        _Float16 h = (_Float16)v;
        B3vh[idx] = h; B3vl[idx] = (_Float16)((v - (float)h) * RS);
    }
}

// =====================================================================
// Fused edge kernel: stage1 MFMA -> LDS transpose -> stage2 MFMA -> gate
// -> linear -> m2h[E][40] fp32 messages. Wave = 16 edges.
// =====================================================================
__global__ __launch_bounds__(256)
void edge_fused(const float* __restrict__ ns, const float* __restrict__ nv,
                const float* __restrict__ edge_s, const float* __restrict__ edge_v,
                const int* __restrict__ ei,
                const _Float16* __restrict__ B1sh, const _Float16* __restrict__ B1sl,
                const _Float16* __restrict__ B1vh, const _Float16* __restrict__ B1vl,
                const _Float16* __restrict__ B2sh, const _Float16* __restrict__ B2sl,
                const _Float16* __restrict__ B2vh, const _Float16* __restrict__ B2vl,
                const float* __restrict__ Lms, const float* __restrict__ Lmv,
                float* __restrict__ m2h, int E)
{
    __shared__ float mT[4][16*41];       // [wave][edge][41] m transpose
    __shared__ float ep[4][2][16*49];    // [wave][{hs,gv}][edge][49]
    const int lane = threadIdx.x & 63;
    const int wv = threadIdx.x >> 6;
    const int e0 = (blockIdx.x*4 + wv) * 16;
    const int q = lane >> 4, n = lane & 15;
    const int e = min(e0 + n, E - 1);
    const int qh = q >> 1, ql = q & 1;
    const int r = ei[e], c2 = ei[E + e];

    // ---------------- stage 1 feature slices ----------------
    float rs_sel[8], rs4[4], rva[2][3], rvs[4][3], csh[8], cv[8][3];
#pragma unroll
    for (int t = 0; t < 8; ++t) rs_sel[t] = ns[(size_t)r*16 + 2*t + qh];
#pragma unroll
    for (int t = 0; t < 4; ++t) rs4[t] = ns[(size_t)r*16 + 4*t + q];
#pragma unroll
    for (int cc = 0; cc < 3; ++cc) {
        rva[0][cc] = nv[(size_t)r*24 + 3*q + cc];
        rva[1][cc] = nv[(size_t)r*24 + 3*(q+4) + cc];
    }
#pragma unroll
    for (int u = 0; u < 4; ++u)
#pragma unroll
        for (int cc = 0; cc < 3; ++cc) rvs[u][cc] = nv[(size_t)r*24 + 3*(2*u+qh) + cc];
    {
        const float4* p = (const float4*)(ns + (size_t)c2*16 + ql*8);
#pragma unroll
        for (int t = 0; t < 2; ++t) { float4 v = p[t]; csh[4*t]=v.x; csh[4*t+1]=v.y; csh[4*t+2]=v.z; csh[4*t+3]=v.w; }
        const float4* pv = (const float4*)(nv + (size_t)c2*24);
        float tmp[24];
#pragma unroll
        for (int t = 0; t < 6; ++t) { float4 v = pv[t]; tmp[4*t]=v.x; tmp[4*t+1]=v.y; tmp[4*t+2]=v.z; tmp[4*t+3]=v.w; }
#pragma unroll
        for (int k = 0; k < 8; ++k) { cv[k][0]=tmp[3*k]; cv[k][1]=tmp[3*k+1]; cv[k][2]=tmp[3*k+2]; }
    }

    const half8* B1sH = (const half8*)B1sh; const half8* B1sL = (const half8*)B1sl;
    const half8* B1vH = (const half8*)B1vh; const half8* B1vL = (const half8*)B1vl;

    // ---- stage1 scalar GEMM: [16e x 320] @ [320 x 16] ----
    {
        floatx4 acc = {0.f,0.f,0.f,0.f}, accR = {0.f,0.f,0.f,0.f};
#pragma unroll
        for (int t = 0; t < 10; ++t) {
            float p[8];
            if (t < 8) {
                const float m = rs_sel[t];
#pragma unroll
                for (int j = 0; j < 8; ++j) p[j] = m * csh[j];
            } else {
                const int u = t - 8;
                const float vx = rva[u][0], vy = rva[u][1], vz = rva[u][2];
#pragma unroll
                for (int j = 0; j < 8; ++j) p[j] = fmaf(vx, cv[j][0], fmaf(vy, cv[j][1], vz*cv[j][2]));
            }
            half8 ah, al; split8s(p, ah, al);
            mfma_tri(ah, al, B1sH[t*64 + lane], B1sL[t*64 + lane], acc, accR);
        }
#pragma unroll
        for (int r2 = 0; r2 < 4; ++r2)
            mT[wv][(q*4 + r2)*41 + n] = acc[r2] + accR[r2]*RSI;
    }
    // ---- stage1 vector GEMMs per component ----
#pragma unroll 1
    for (int c = 0; c < 3; ++c) {
        const int c1 = (c+1)%3, c2i = (c+2)%3;
        floatx4 acc = {0.f,0.f,0.f,0.f}, accR = {0.f,0.f,0.f,0.f};
#pragma unroll
        for (int t = 0; t < 10; ++t) {
            float p[8];
            if (t < 4) {
                const float m = rs4[t];
#pragma unroll
                for (int j = 0; j < 8; ++j) p[j] = m * cv[j][c];
            } else if (t < 8) {
                const float m = rvs[t-4][c];
#pragma unroll
                for (int j = 0; j < 8; ++j) p[j] = m * csh[j];
            } else {
                const int u = t - 8;
                const float v1 = rva[u][c1], v2 = rva[u][c2i];
#pragma unroll
                for (int j = 0; j < 8; ++j) p[j] = v1*cv[j][c2i] - v2*cv[j][c1];
            }
            half8 ah, al; split8s(p, ah, al);
            mfma_tri(ah, al, B1vH[t*64 + lane], B1vL[t*64 + lane], acc, accR);
        }
        if (n < 8) {
#pragma unroll
            for (int r2 = 0; r2 < 4; ++r2)
                mT[wv][(q*4 + r2)*41 + 16 + 3*n + c] = acc[r2] + accR[r2]*RSI;
        }
    }
    __syncthreads();

    // ---------------- stage 2 inputs ----------------
    float msr[4], mva[2][3], es[8], ev[8][3];
#pragma unroll
    for (int t = 0; t < 4; ++t) msr[t] = mT[wv][n*41 + 4*t + q];
#pragma unroll
    for (int u = 0; u < 2; ++u)
#pragma unroll
        for (int cc = 0; cc < 3; ++cc) mva[u][cc] = mT[wv][n*41 + 16 + 3*(4*u+q) + cc];
    {
        const float4* p = (const float4*)(edge_s + (size_t)e*8);
#pragma unroll
        for (int t = 0; t < 2; ++t) { float4 v = p[t]; es[4*t]=v.x; es[4*t+1]=v.y; es[4*t+2]=v.z; es[4*t+3]=v.w; }
        const float4* pv = (const float4*)(edge_v + (size_t)e*24);
        float tmp[24];
#pragma unroll
        for (int t = 0; t < 6; ++t) { float4 v = pv[t]; tmp[4*t]=v.x; tmp[4*t+1]=v.y; tmp[4*t+2]=v.z; tmp[4*t+3]=v.w; }
#pragma unroll
        for (int k = 0; k < 8; ++k) { ev[k][0]=tmp[3*k]; ev[k][1]=tmp[3*k+1]; ev[k][2]=tmp[3*k+2]; }
    }

    const half8* B2sH = (const half8*)B2sh; const half8* B2sL = (const half8*)B2sl;
    const half8* B2vH = (const half8*)B2vh; const half8* B2vL = (const half8*)B2vl;

    // ---- stage2 scalar GEMM: [16e x 192] @ [192 x 48] ----
    floatx4 accs[3], accsR[3];
#pragma unroll
    for (int t = 0; t < 3; ++t) { accs[t] = (floatx4){0.f,0.f,0.f,0.f}; accsR[t] = (floatx4){0.f,0.f,0.f,0.f}; }
#pragma unroll
    for (int t = 0; t < 6; ++t) {
        float p[8];
        if (t < 4) {
            const float m = msr[t];
#pragma unroll
            for (int j = 0; j < 8; ++j) p[j] = m * es[j];
        } else {
            const int u = t - 4;
            const float vx = mva[u][0], vy = mva[u][1], vz = mva[u][2];
#pragma unroll
            for (int j = 0; j < 8; ++j) p[j] = fmaf(vx, ev[j][0], fmaf(vy, ev[j][1], vz*ev[j][2]));
        }
        half8 ah, al; split8s(p, ah, al);
#pragma unroll
        for (int tn = 0; tn < 3; ++tn)
            mfma_tri(ah, al, B2sH[(tn*6 + t)*64 + lane], B2sL[(tn*6 + t)*64 + lane], accs[tn], accsR[tn]);
    }

    float* hsL = &ep[wv][0][0];
    float* gvL = &ep[wv][1][0];
#pragma unroll
    for (int t = 0; t < 3; ++t)
#pragma unroll
        for (int r2 = 0; r2 < 4; ++r2) {
            const int row = q*4 + r2;
            const float v = accs[t][r2] + accsR[t][r2]*RSI;
            if (t < 2) hsL[row*49 + t*16 + n] = v / (1.f + __expf(-v)) * C_LS;
            else       hsL[row*49 + 32 + n] = v;
        }
    __syncthreads();

    // scalar epilogue
    {
        float os[4] = {0.f, 0.f, 0.f, 0.f};
#pragma unroll 4
        for (int s = 0; s < 32; ++s) {
            const float hv_ = hsL[n*49 + s];
            const float4 w = *(const float4*)(Lms + s*16 + 4*q);
            os[0] = fmaf(hv_, w.x, os[0]); os[1] = fmaf(hv_, w.y, os[1]);
            os[2] = fmaf(hv_, w.z, os[2]); os[3] = fmaf(hv_, w.w, os[3]);
        }
        if (e0 + n < E) {
#pragma unroll
            for (int u = 0; u < 4; ++u)
                m2h[(size_t)(e0 + n)*40 + 4*q + u] = os[u];
        }
    }

    // ---- stage2 vector GEMMs ----
    floatx4 accv[3];
#pragma unroll 1
    for (int c = 0; c < 3; ++c) {
        const int c1 = (c+1)%3, c2i = (c+2)%3;
        floatx4 acc = {0.f,0.f,0.f,0.f}, accR = {0.f,0.f,0.f,0.f};
#pragma unroll
        for (int t = 0; t < 8; ++t) {
            float p[8];
            if (t < 4) {
                const float m = msr[t];
#pragma unroll
                for (int j = 0; j < 8; ++j) p[j] = m * ev[j][c];
            } else if (t < 6) {
                const float m = mva[t-4][c];
#pragma unroll
                for (int j = 0; j < 8; ++j) p[j] = m * es[j];
            } else {
                const int u = t - 6;
                const float v1 = mva[u][c1], v2 = mva[u][c2i];
#pragma unroll
                for (int j = 0; j < 8; ++j) p[j] = v1*ev[j][c2i] - v2*ev[j][c1];
            }
            half8 ah, al; split8s(p, ah, al);
            mfma_tri(ah, al, B2vH[t*64 + lane], B2vL[t*64 + lane], acc, accR);
        }
#pragma unroll
        for (int r2 = 0; r2 < 4; ++r2) acc[r2] = acc[r2] + accR[r2]*RSI;
        accv[c] = acc;
    }
#pragma unroll
    for (int r2 = 0; r2 < 4; ++r2) {
        const int row = q*4 + r2;
        const float gt = C_LV / (1.f + __expf(-hsL[row*49 + 32 + n]));
#pragma unroll
        for (int c = 0; c < 3; ++c) gvL[row*49 + c*16 + n] = accv[c][r2] * gt;
    }
    __syncthreads();

    // vector epilogue
    {
        float ov[3][2] = {{0.f,0.f},{0.f,0.f},{0.f,0.f}};
#pragma unroll 4
        for (int k = 0; k < 16; ++k) {
            const float2 w = *(const float2*)(Lmv + k*8 + 2*q);
#pragma unroll
            for (int c = 0; c < 3; ++c) {
                const float gv = gvL[n*49 + c*16 + k];
                ov[c][0] = fmaf(gv, w.x, ov[c][0]);
                ov[c][1] = fmaf(gv, w.y, ov[c][1]);
            }
        }
        if (e0 + n < E) {
#pragma unroll
            for (int o2 = 0; o2 < 2; ++o2)
#pragma unroll
                for (int c = 0; c < 3; ++c)
                    m2h[(size_t)(e0 + n)*40 + 16 + 3*(2*q + o2) + c] = ov[c][o2];
        }
    }
}

// =====================================================================
// CSR build
// =====================================================================
__global__ void hist_k(const int* __restrict__ ei, int* __restrict__ deg, int E) {
    const int e = blockIdx.x*256 + threadIdx.x;
    if (e < E) atomicAdd(&deg[ei[E + e]], 1);
}
__global__ void scan_k(const int* __restrict__ deg, int* __restrict__ offs,
                       int* __restrict__ pos, int N) {
    __shared__ int sm[1024];
    const int t = threadIdx.x;
    const int chunk = (N + 1023) / 1024;
    const int lo = t * chunk, hi = min(lo + chunk, N);
    int s = 0;
    for (int i = lo; i < hi; ++i) s += deg[i];
    sm[t] = s; __syncthreads();
    for (int off = 1; off < 1024; off <<= 1) {
        int v = (t >= off) ? sm[t - off] : 0;
        __syncthreads();
        sm[t] += v;
        __syncthreads();
    }
    int base = sm[t] - s;
    for (int i = lo; i < hi; ++i) { offs[i] = base; pos[i] = base; base += deg[i]; }
}
__global__ void fill_k(const int* __restrict__ ei, int* __restrict__ pos,
                       int* __restrict__ order, int E) {
    const int e = blockIdx.x*256 + threadIdx.x;
    if (e < E) { int p = atomicAdd(&pos[ei[E + e]], 1); order[p] = e; }
}

// =====================================================================
// agg_k: CSR gather-aggregate fp32 messages -> agg[N][40]
// =====================================================================
__global__ __launch_bounds__(256)
void agg_k(const float* __restrict__ m2h,
           const int* __restrict__ deg, const int* __restrict__ offs,
           const int* __restrict__ order,
           float* __restrict__ agg, int N)
{
    const int n = blockIdx.x*256 + threadIdx.x;
    if (n >= N) return;
    float a[40];
#pragma unroll
    for (int u = 0; u < 40; ++u) a[u] = 0.f;
    const int cnt = deg[n], base = offs[n];
    for (int t = 0; t < cnt; ++t) {
        const int id = order[base + t];
        const float4* mp = (const float4*)(m2h + (size_t)id*40);
#pragma unroll
        for (int u = 0; u < 10; ++u) {
            float4 v = mp[u];
            a[4*u] += v.x; a[4*u+1] += v.y; a[4*u+2] += v.z; a[4*u+3] += v.w;
        }
    }
    float4* o = (float4*)(agg + (size_t)n*40);
#pragma unroll
    for (int u = 0; u < 10; ++u) o[u] = make_float4(a[4*u], a[4*u+1], a[4*u+2], a[4*u+3]);
}

// =====================================================================
// node_mfma: TP(node, agg) via split-MFMA + gate + linear -> out[N,40]
// Wave = 16 nodes. Same fragment scheme as edge stage 1, Tn=3 scalar, 16-col vector.
// =====================================================================
__global__ __launch_bounds__(256)
void node_mfma(const float* __restrict__ ns, const float* __restrict__ nv,
               const float* __restrict__ agg,
               const _Float16* __restrict__ B3sh, const _Float16* __restrict__ B3sl,
               const _Float16* __restrict__ B3vh, const _Float16* __restrict__ B3vl,
               const float* __restrict__ Lus, const float* __restrict__ Luv,
               float* __restrict__ out, int N)
{
    __shared__ float ep[4][2][16*49];    // [wave][{hs,gv}][node][49]
    const int lane = threadIdx.x & 63;
    const int wv = threadIdx.x >> 6;
    const int n0 = (blockIdx.x*4 + wv) * 16;
    const int q = lane >> 4, n = lane & 15;
    const int nd = min(n0 + n, N - 1);
    const int qh = q >> 1, ql = q & 1;

    // row side = node features
    float rs_sel[8], rs4[4], rva[2][3], rvs[4][3];
#pragma unroll
    for (int t = 0; t < 8; ++t) rs_sel[t] = ns[(size_t)nd*16 + 2*t + qh];
#pragma unroll
    for (int t = 0; t < 4; ++t) rs4[t] = ns[(size_t)nd*16 + 4*t + q];
#pragma unroll
    for (int cc = 0; cc < 3; ++cc) {
        rva[0][cc] = nv[(size_t)nd*24 + 3*q + cc];
        rva[1][cc] = nv[(size_t)nd*24 + 3*(q+4) + cc];
    }
#pragma unroll
    for (int u = 0; u < 4; ++u)
#pragma unroll
        for (int cc = 0; cc < 3; ++cc) rvs[u][cc] = nv[(size_t)nd*24 + 3*(2*u+qh) + cc];
    // col side = aggregated features
    float csh[8], cv[8][3];
    {
        const float4* p = (const float4*)(agg + (size_t)nd*40 + ql*8);
#pragma unroll
        for (int t = 0; t < 2; ++t) { float4 v = p[t]; csh[4*t]=v.x; csh[4*t+1]=v.y; csh[4*t+2]=v.z; csh[4*t+3]=v.w; }
        const float4* pv = (const float4*)(agg + (size_t)nd*40 + 16);
        float tmp[24];
#pragma unroll
        for (int t = 0; t < 6; ++t) { float4 v = pv[t]; tmp[4*t]=v.x; tmp[4*t+1]=v.y; tmp[4*t+2]=v.z; tmp[4*t+3]=v.w; }
#pragma unroll
        for (int k = 0; k < 8; ++k) { cv[k][0]=tmp[3*k]; cv[k][1]=tmp[3*k+1]; cv[k][2]=tmp[3*k+2]; }
    }

    const half8* B3sH = (const half8*)B3sh; const half8* B3sL = (const half8*)B3sl;
    const half8* B3vH = (const half8*)B3vh; const half8* B3vL = (const half8*)B3vl;

    // ---- scalar GEMM: [16n x 320] @ [320 x 48] ----
    floatx4 accs[3], accsR[3];
#pragma unroll
    for (int t = 0; t < 3; ++t) { accs[t] = (floatx4){0.f,0.f,0.f,0.f}; accsR[t] = (floatx4){0.f,0.f,0.f,0.f}; }
#pragma unroll
    for (int t = 0; t < 10; ++t) {
        float p[8];
        if (t < 8) {
            const float m = rs_sel[t];
#pragma unroll
            for (int j = 0; j < 8; ++j) p[j] = m * csh[j];
        } else {
            const int u = t - 8;
            const float vx = rva[u][0], vy = rva[u][1], vz = rva[u][2];
#pragma unroll
            for (int j = 0; j < 8; ++j) p[j] = fmaf(vx, cv[j][0], fmaf(vy, cv[j][1], vz*cv[j][2]));
        }
        half8 ah, al; split8s(p, ah, al);
#pragma unroll
        for (int tn = 0; tn < 3; ++tn)
            mfma_tri(ah, al, B3sH[(tn*10 + t)*64 + lane], B3sL[(tn*10 + t)*64 + lane], accs[tn], accsR[tn]);
    }

    float* hsL = &ep[wv][0][0];
    float* gvL = &ep[wv][1][0];
#pragma unroll
    for (int t = 0; t < 3; ++t)
#pragma unroll
        for (int r2 = 0; r2 < 4; ++r2) {
            const int row = q*4 + r2;
            const float v = accs[t][r2] + accsR[t][r2]*RSI;
            if (t < 2) hsL[row*49 + t*16 + n] = v / (1.f + __expf(-v)) * C_LS;
            else       hsL[row*49 + 32 + n] = v;
        }
    __syncthreads();

    // scalar epilogue -> out[:, 0:16]
    {
        float os[4] = {0.f, 0.f, 0.f, 0.f};
#pragma unroll 4
        for (int s = 0; s < 32; ++s) {
            const float hv_ = hsL[n*49 + s];
            const float4 w = *(const float4*)(Lus + s*16 + 4*q);
            os[0] = fmaf(hv_, w.x, os[0]); os[1] = fmaf(hv_, w.y, os[1]);
            os[2] = fmaf(hv_, w.z, os[2]); os[3] = fmaf(hv_, w.w, os[3]);
        }
        if (n0 + n < N) {
#pragma unroll
            for (int u = 0; u < 4; ++u)
                out[(size_t)(n0 + n)*40 + 4*q + u] = os[u];
        }
    }

    // ---- vector GEMMs per component: [16n x 320] @ [320 x 16] ----
    floatx4 accv[3];
#pragma unroll 1
    for (int c = 0; c < 3; ++c) {
        const int c1 = (c+1)%3, c2i = (c+2)%3;
        floatx4 acc = {0.f,0.f,0.f,0.f}, accR = {0.f,0.f,0.f,0.f};
#pragma unroll
        for (int t = 0; t < 10; ++t) {
            float p[8];
            if (t < 4) {
                const float m = rs4[t];
#pragma unroll
                for (int j = 0; j < 8; ++j) p[j] = m * cv[j][c];
            } else if (t < 8) {
                const float m = rvs[t-4][c];
#pragma unroll
                for (int j = 0; j < 8; ++j) p[j] = m * csh[j];
            } else {
                const int u = t - 8;
                const float v1 = rva[u][c1], v2 = rva[u][c2i];
#pragma unroll
                for (int j = 0; j < 8; ++j) p[j] = v1*cv[j][c2i] - v2*cv[j][c1];
            }
            half8 ah, al; split8s(p, ah, al);
            mfma_tri(ah, al, B3vH[t*64 + lane], B3vL[t*64 + lane], acc, accR);
        }
#pragma unroll
        for (int r2 = 0; r2 < 4; ++r2) acc[r2] = acc[r2] + accR[r2]*RSI;
        accv[c] = acc;
    }
#pragma unroll
    for (int r2 = 0; r2 < 4; ++r2) {
        const int row = q*4 + r2;
        const float gt = C_LV / (1.f + __expf(-hsL[row*49 + 32 + n]));
#pragma unroll
        for (int c = 0; c < 3; ++c) gvL[row*49 + c*16 + n] = accv[c][r2] * gt;
    }
    __syncthreads();

    // vector epilogue -> out[:, 16:40]
    {
        float ov[3][2] = {{0.f,0.f},{0.f,0.f},{0.f,0.f}};
#pragma unroll 4
        for (int k = 0; k < 16; ++k) {
            const float2 w = *(const float2*)(Luv + k*8 + 2*q);
#pragma unroll
            for (int c = 0; c < 3; ++c) {
                const float gv = gvL[n*49 + c*16 + k];
                ov[c][0] = fmaf(gv, w.x, ov[c][0]);
                ov[c][1] = fmaf(gv, w.y, ov[c][1]);
            }
        }
        if (n0 + n < N) {
#pragma unroll
            for (int o2 = 0; o2 < 2; ++o2)
#pragma unroll
                for (int c = 0; c < 3; ++c)
                    out[(size_t)(n0 + n)*40 + 16 + 3*(2*q + o2) + c] = ov[c][o2];
        }
    }
}

// =====================================================================
extern "C" void kernel_launch(void* const* d_in, const int* in_sizes, int n_in,
                              void* d_out, int out_size, void* d_ws, size_t ws_size,
                              hipStream_t stream) {
    const float* node_s = (const float*)d_in[0];
    const float* node_v = (const float*)d_in[1];
    const float* edge_s = (const float*)d_in[3];
    const float* edge_v = (const float*)d_in[4];
    const int*   ei     = (const int*)d_in[5];
    const float* W1ss = (const float*)d_in[6];
    const float* W1sv = (const float*)d_in[7];
    const float* W1vs = (const float*)d_in[8];
    const float* W1vvs= (const float*)d_in[9];
    const float* W1vvv= (const float*)d_in[10];
    const float* W2ss = (const float*)d_in[11];
    const float* W2sv = (const float*)d_in[12];
    const float* W2vs = (const float*)d_in[13];
    const float* W2vvs= (const float*)d_in[14];
    const float* W2vvv= (const float*)d_in[15];
    const float* Lms  = (const float*)d_in[16];
    const float* Lmv  = (const float*)d_in[17];
    const float* W3ss = (const float*)d_in[18];
    const float* W3sv = (const float*)d_in[19];
    const float* W3vs = (const float*)d_in[20];
    const float* W3vvs= (const float*)d_in[21];
    const float* W3vvv= (const float*)d_in[22];
    const float* Lus  = (const float*)d_in[23];
    const float* Luv  = (const float*)d_in[24];

    float* out = (float*)d_out;
    const int N = in_sizes[0] / 16;
    const int E = in_sizes[5] / 2;

    // ws layout: fp16 B-frags, fp32 messages, fp32 agg, CSR ints
    _Float16* B1sh = (_Float16*)d_ws;             // 5120
    _Float16* B1sl = B1sh + 5120;
    _Float16* B1vh = B1sl + 5120;
    _Float16* B1vl = B1vh + 5120;
    _Float16* B2sh = B1vl + 5120;                 // 9216
    _Float16* B2sl = B2sh + 9216;
    _Float16* B2vh = B2sl + 9216;                 // 4096
    _Float16* B2vl = B2vh + 4096;
    _Float16* B3sh = B2vl + 4096;                 // 15360
    _Float16* B3sl = B3sh + 15360;
    _Float16* B3vh = B3sl + 15360;                // 5120
    _Float16* B3vl = B3vh + 5120;                 // ends at 88064 halves = 176128 B
    float* m2h = (float*)((char*)d_ws + 176128);  // [E][40] fp32
    float* agg = m2h + (size_t)40*E;              // [N][40] fp32
    int* deg   = (int*)(agg + (size_t)40*N);      // N
    int* offs  = deg + N;
    int* pos   = offs + N;
    int* order = pos + N;                         // E

    hipMemsetAsync(deg, 0, (size_t)N * sizeof(int), stream);

    prep_w<<<1, 256, 0, stream>>>(W1ss, W1sv, W1vs, W1vvs, W1vvv,
                                  W2ss, W2sv, W2vs, W2vvs, W2vvv,
                                  W3ss, W3sv, W3vs, W3vvs, W3vvv,
                                  B1sh, B1sl, B1vh, B1vl, B2sh, B2sl, B2vh, B2vl,
                                  B3sh, B3sl, B3vh, B3vl);

    hist_k<<<(E + 255)/256, 256, 0, stream>>>(ei, deg, E);
    scan_k<<<1, 1024, 0, stream>>>(deg, offs, pos, N);
    fill_k<<<(E + 255)/256, 256, 0, stream>>>(ei, pos, order, E);

    const int tpblocks = (E + 63) / 64;   // 4 waves/block, 16 edges/wave
    edge_fused<<<tpblocks, 256, 0, stream>>>(
        node_s, node_v, edge_s, edge_v, ei,
        B1sh, B1sl, B1vh, B1vl, B2sh, B2sl, B2vh, B2vl,
        Lms, Lmv, m2h, E);

    agg_k<<<(N + 255)/256, 256, 0, stream>>>(m2h, deg, offs, order, agg, N);

    const int ndblocks = ((N + 15)/16 + 3) / 4;   // 4 waves/block, 16 nodes/wave
    node_mfma<<<ndblocks, 256, 0, stream>>>(
        node_s, node_v, agg, B3sh, B3sl, B3vh, B3vl, Lus, Luv, out, N);
}